// Round 6
// baseline (415.351 us; speedup 1.0000x reference)
//
#include <hip/hip_runtime.h>
#include <cmath>

#define NC 6
#define CF 64
#define HH 88
#define WW 160
#define NPIX 14080     // 88*160
#define NVOX 200000
#define VPRE 64
#define NGRP 782       // ceil(200000/256)
#define NTRB 1320      // 6*220 transpose tiles

typedef unsigned int u32;

#define FEATT_BYTES  (6u * 64u * 14080u * 4u)            // 21,626,880 (256-aligned)
// ---- layout: per-group counts + fixed per-group record slots ----
#define CNT1_OFF     (FEATT_BYTES)                       // NGRP ints (pad 4096)
#define CNT2_OFF     (CNT1_OFF + 4096u)
#define REC1_OFF     (CNT2_OFF + 4096u)                  // NVOX float4 (g*256+i)
#define REC2_OFF     (REC1_OFF + (u32)NVOX * 16u)        // 2*NVOX float4 (g*512+2i+h)
#define WS_NEED      ((size_t)REC2_OFF + (size_t)NVOX * 32u)   // 31,235,072
// ---- OLD layout (fallback path, round-3 proven) ----
#define OCNT_OFF     (FEATT_BYTES)
#define OREC1_OFF    (OCNT_OFF + 256u)
#define OREC2_OFF    (OREC1_OFF + (u32)NVOX * 16u)
#define WS_NEED_OLD  ((size_t)OREC2_OFF + (size_t)NVOX * 32u)  // 31,227,136

__device__ __forceinline__ float elu1(float x) { return x > 0.0f ? x : expm1f(x); }

// bilinear gather: voxel uniform across wave, lane = channel. Math identical to prior rounds.
__device__ __forceinline__ float gather_bilin(const float* __restrict__ fsrc, int useT,
                                              int lane, int cam, float x, float y) {
    float x0f = floorf(x), y0f = floorf(y);
    float wx1 = x - x0f, wx0 = 1.0f - wx1;
    float wy1 = y - y0f, wy0 = 1.0f - wy1;
    float x1f = x0f + 1.0f, y1f = y0f + 1.0f;
    float bx0 = (x0f >= 0.0f && x0f <= 159.0f) ? 1.0f : 0.0f;
    float bx1 = (x1f >= 0.0f && x1f <= 159.0f) ? 1.0f : 0.0f;
    float by0 = (y0f >= 0.0f && y0f <= 87.0f) ? 1.0f : 0.0f;
    float by1 = (y1f >= 0.0f && y1f <= 87.0f) ? 1.0f : 0.0f;
    int ix0 = (int)fminf(fmaxf(x0f, 0.0f), 159.0f);
    int ix1 = (int)fminf(fmaxf(x1f, 0.0f), 159.0f);
    int iy0 = (int)fminf(fmaxf(y0f, 0.0f), 87.0f);
    int iy1 = (int)fminf(fmaxf(y1f, 0.0f), 87.0f);
    int A = useT ? 64 : 1;
    int Boff = useT ? (cam * NPIX * 64 + lane) : ((cam * 64 + lane) * NPIX);
    float v00 = fsrc[(iy0 * WW + ix0) * A + Boff];
    float v01 = fsrc[(iy1 * WW + ix0) * A + Boff];
    float v10 = fsrc[(iy0 * WW + ix1) * A + Boff];
    float v11 = fsrc[(iy1 * WW + ix1) * A + Boff];
    float fv;                                        // reference corner order
    fv  = (wx0 * wy0 * bx0 * by0) * v00;
    fv += (wx0 * wy1 * bx0 * by1) * v01;
    fv += (wx1 * wy0 * bx1 * by0) * v10;
    fv += (wx1 * wy1 * bx1 * by1) * v11;
    return fv;
}

// =====================================================================
// K1: transpose ∥ zero-output ∥ geometry (per-group slots, NO atomics).
// blocks [0,NTRB): transpose tile; blocks [NTRB, NTRB+NGRP): geom group.
// All blocks additionally zero a grid-stride slice of the output.
// (unchanged from round 5 — proven)
// =====================================================================
__global__ __launch_bounds__(256) void vox_prep(
    const float* __restrict__ feats,
    float* __restrict__ featT,
    const float* __restrict__ mask,
    const float* __restrict__ Kg,
    const float* __restrict__ ext,
    float* __restrict__ outp,
    float4* __restrict__ rec1,       // NVOX slots, g*256+i
    float4* __restrict__ rec2,       // 2*NVOX slots, g*512+2i+h
    int* __restrict__ cnt1g,         // [NGRP]
    int* __restrict__ cnt2g)         // [NGRP]
{
    __shared__ __align__(16) float s_buf[4290];      // 17160 B union
    __shared__ float s_ext[72];
    __shared__ float s_K[54];
    __shared__ int s_c1, s_c2;

    int tid = threadIdx.x;
    int lane = tid & 63;
    int wv = tid >> 6;
    int bid = blockIdx.x;

    if (bid < NTRB) {
        // ---- transpose tile ----
        int c = bid / 220;
        int p0 = (bid - c * 220) * 64;
        for (int r = wv; r < 64; r += 4)
            s_buf[r * 65 + lane] = feats[(c * 64 + r) * NPIX + p0 + lane];
        __syncthreads();
        for (int r = wv; r < 64; r += 4)
            featT[((c * NPIX) + p0 + r) * 64 + lane] = s_buf[lane * 65 + r];
    } else {
        // ---- geometry group (per-group slot output) ----
        int g = bid - NTRB;
        float4* s_r1 = (float4*)s_buf;               // 256 recs (4096 B)
        float4* s_r2 = ((float4*)s_buf) + 256;       // 512 recs (8192 B)
        if (tid == 0) { s_c1 = 0; s_c2 = 0; }
        if (tid >= 64 && tid < 136) {
            int i = tid - 64;
            s_ext[i] = ext[(i / 12) * 16 + (i % 12)];
        }
        if (tid >= 160 && tid < 214) {
            int i = tid - 160; int cam = i / 9; int e = i - cam * 9;
            s_K[i] = Kg[cam * 16 + (e / 3) * 4 + (e % 3)];
        }
        __syncthreads();
        int n = g * 256 + tid;
        if (n < NVOX) {
            #pragma clang fp contract(off)
            int xi = n % 100;
            int t = n / 100;
            int yi = t % 100;
            int zi = t / 100;
            float X = -50.0f + (float)xi;
            float Y = -50.0f + (float)yi;
            float Z = -15.0f + 1.5f * (float)zi;
            int cc = 0, cam0 = 0, cam1 = 0;
            float ax = 0.f, ay = 0.f, az = 0.f, bx = 0.f, by = 0.f, bz = 0.f;
            #pragma unroll
            for (int cam = 0; cam < NC; ++cam) {
                const float* E = s_ext + cam * 12;
                const float* Kk = s_K + cam * 9;
                float vl0 = E[0]*X + E[1]*Y + E[2]*Z + E[3];
                float vl1 = E[4]*X + E[5]*Y + E[6]*Z + E[7];
                float vl2 = E[8]*X + E[9]*Y + E[10]*Z + E[11];
                float c0 = Kk[0]*vl0 + Kk[1]*vl1 + Kk[2]*vl2;
                float c1 = Kk[3]*vl0 + Kk[4]*vl1 + Kk[5]*vl2;
                float c2 = Kk[6]*vl0 + Kk[7]*vl1 + Kk[8]*vl2;
                float pz = c2 + 1e-8f;
                float px = c0 / pz;
                float py = c1 / pz;
                float gx = (px / 159.0f - 0.5f) * 2.0f;
                float gy = (py / 87.0f - 0.5f) * 2.0f;
                float x = ((gx + 1.0f) * 0.5f) * 159.0f;
                float y = ((gy + 1.0f) * 0.5f) * 87.0f;
                float xr = rintf(x), yr = rintf(y);
                bool nv = (xr >= 0.0f) && (xr <= 159.0f) && (yr >= 0.0f) && (yr <= 87.0f);
                float mval = 0.0f;
                if (nv) mval = mask[(cam * HH + (int)yr) * WW + (int)xr];
                bool ok = (mval > 0.5f) && (vl2 > 0.0f) &&
                          !((gx > 1.0f) || (gx < -1.0f) || (gy > 1.0f) || (gy < -1.0f));
                if (ok) {
                    if (cc == 0) { ax = x; ay = y; az = vl2; cam0 = cam; }
                    else if (cc == 1) { bx = x; by = y; bz = vl2; cam1 = cam; }
                    ++cc;
                }
            }
            if (cc == 1) {
                int s = atomicAdd(&s_c1, 1);
                s_r1[s] = make_float4(ax, ay, az, __int_as_float((n << 3) | cam0));
            } else if (cc == 2) {
                int s = atomicAdd(&s_c2, 1);
                s_r2[2 * s + 0] = make_float4(ax, ay, az, __int_as_float((n << 3) | cam0));
                s_r2[2 * s + 1] = make_float4(bx, by, bz, __int_as_float((n << 3) | cam1));
            }
        }
        __syncthreads();
        int c1 = s_c1, c2 = s_c2;
        if (tid == 0) { cnt1g[g] = c1; cnt2g[g] = c2; }
        for (int i = tid; i < c1; i += 256) rec1[g * 256 + i] = s_r1[i];
        for (int i = tid; i < 2 * c2; i += 256) rec2[g * 512 + i] = s_r2[i];
    }

    // ---- grid-stride zero of the output window (independent of above) ----
    {
        float4* o4 = (float4*)outp;
        const int n4 = VPRE * NVOX / 4;
        const int stride = (NTRB + NGRP) * 256;
        for (int i = bid * 256 + tid; i < n4; i += stride)
            o4[i] = make_float4(0.f, 0.f, 0.f, 0.f);
    }
}

// inclusive prefix over NGRP counts (512-thread block version).
// s_scr = 512-int scratch (aliased into s_F), s_P = output
__device__ __forceinline__ void scan_counts(const int* __restrict__ cg,
                                            int* s_scr, int* s_P, int tid) {
    int base = tid * 2;
    int v0 = (base + 0 < NGRP) ? cg[base + 0] : 0;
    int v1 = (base + 1 < NGRP) ? cg[base + 1] : 0;
    int s1 = v0 + v1;
    s_scr[tid] = s1;
    __syncthreads();
    for (int off = 1; off < 512; off <<= 1) {
        int x = s_scr[tid];
        int y = (tid >= off) ? s_scr[tid - off] : 0;
        __syncthreads();
        s_scr[tid] = x + y;
        __syncthreads();
    }
    int excl = (tid > 0) ? s_scr[tid - 1] : 0;
    if (base + 0 < NGRP) s_P[base + 0] = excl + v0;
    if (base + 1 < NGRP) s_P[base + 1] = excl + v0 + v1;
    __syncthreads();
}

__device__ __forceinline__ int bsearch_grp(const int* __restrict__ P, int k) {
    int lo = 0, hi = NGRP - 1;
    while (lo < hi) { int mid = (lo + hi) >> 1; if (P[mid] > k) hi = mid; else lo = mid + 1; }
    return lo;
}

// =====================================================================
// K2: comp over virtually-compacted 64-entry tiles.
// 512 threads = 8 waves per tile: serial gather chain per wave is 8
// entries (was 16), 8 output rows per wave. Low VGPR (launch_bounds
// 512,8 caps at 64) so 4 blocks x 8 waves = 32 waves/CU admissible.
// =====================================================================
__global__ __launch_bounds__(512, 8) void vox_comp2(
    const float* __restrict__ featT,
    const float* __restrict__ wno,   // [64][65]
    const float* __restrict__ bno,   // [64]
    const float* __restrict__ wo,    // [64][130]
    const float* __restrict__ bo,    // [64]
    float* __restrict__ outp,        // [64][200000]
    const float4* __restrict__ rec1,
    const float4* __restrict__ rec2,
    const int* __restrict__ cnt1g,
    const int* __restrict__ cnt2g)
{
    __shared__ __align__(16) float s_F[65 * 66];     // 17160 B (scan scratch aliases here)
    __shared__ float4 s_rec[128];
    __shared__ int s_vox[64];
    __shared__ int s_P1[NGRP];
    __shared__ int s_P2[NGRP];

    int tid = threadIdx.x;
    int lane = tid & 63;
    int wv = tid >> 6;                               // 0..7
    int wvu = __builtin_amdgcn_readfirstlane(wv);
    int obase = wvu * 8;

    scan_counts(cnt1g, (int*)s_F, s_P1, tid);
    scan_counts(cnt2g, (int*)s_F, s_P2, tid);
    int n1 = s_P1[NGRP - 1], n2 = s_P2[NGRP - 1];
    int T1 = (n1 + 63) >> 6;
    int T2 = (n2 + 63) >> 6;
    int TT = T1 + T2;

    for (int t = blockIdx.x; t < TT; t += gridDim.x) {
        if (t < T1) {
            // ---------------- count == 1 tile ----------------
            int e0 = t << 6;
            int tl = min(64, n1 - e0);
            if (tid < tl) {
                int k = e0 + tid;
                int g = bsearch_grp(s_P1, k);
                int l = k - ((g > 0) ? s_P1[g - 1] : 0);
                s_rec[tid] = rec1[g * 256 + l];
            }
            __syncthreads();
            for (int e = wv; e < tl; e += 8) {
                float4 r = s_rec[e];                 // wave-uniform LDS broadcast
                int meta = __float_as_int(r.w);
                int cam = meta & 7;
                float fv = gather_bilin(featT, 1, lane, cam, r.x, r.y);
                s_F[lane * 66 + e] = fv;
                if (lane == 0) { s_F[64 * 66 + e] = r.z / 100.0f; s_vox[e] = meta >> 3; }
            }
            __syncthreads();
            float acc[8];
            #pragma unroll
            for (int o = 0; o < 8; ++o) acc[o] = bno[obase + o];
            for (int cg2 = 0; cg2 < 64; cg2 += 4) {
                float f0 = s_F[(cg2 + 0) * 66 + lane];
                float f1 = s_F[(cg2 + 1) * 66 + lane];
                float f2 = s_F[(cg2 + 2) * 66 + lane];
                float f3 = s_F[(cg2 + 3) * 66 + lane];
                #pragma unroll
                for (int o = 0; o < 8; ++o) {
                    const float* wr = wno + (obase + o) * 65 + cg2;
                    acc[o] += wr[0] * f0; acc[o] += wr[1] * f1;
                    acc[o] += wr[2] * f2; acc[o] += wr[3] * f3;
                }
            }
            {
                float fd = s_F[64 * 66 + lane];
                #pragma unroll
                for (int o = 0; o < 8; ++o) acc[o] += wno[(obase + o) * 65 + 64] * fd;
            }
            if (lane < tl) {
                size_t col = (size_t)s_vox[lane];
                #pragma unroll
                for (int o = 0; o < 8; ++o)
                    outp[(size_t)(obase + o) * NVOX + col] = elu1(acc[o]);
            }
            __syncthreads();
        } else {
            // ---------------- count == 2 tile: two passes ----------------
            int tt = t - T1;
            int e0 = tt << 6;
            int tl = min(64, n2 - e0);
            if (tid < 2 * tl) {
                int p = tid >> 1, h = tid & 1;
                int k = e0 + p;
                int g = bsearch_grp(s_P2, k);
                int l = k - ((g > 0) ? s_P2[g - 1] : 0);
                s_rec[tid] = rec2[g * 512 + 2 * l + h];
            }
            __syncthreads();
            // pass A gather: cams {0,3,4}
            for (int e = wv; e < tl; e += 8) {
                float4 r0 = s_rec[2 * e + 0];
                float4 r1 = s_rec[2 * e + 1];
                int m0 = __float_as_int(r0.w), m1 = __float_as_int(r1.w);
                int ca = m0 & 7, cb = m1 & 7;
                float fg = 0.0f, dd = 0.0f;
                if (!(ca == 1 || ca == 2 || ca == 5)) {
                    fg += gather_bilin(featT, 1, lane, ca, r0.x, r0.y);
                    dd += r0.z / 100.0f;
                }
                if (!(cb == 1 || cb == 2 || cb == 5)) {
                    fg += gather_bilin(featT, 1, lane, cb, r1.x, r1.y);
                    dd += r1.z / 100.0f;
                }
                s_F[lane * 66 + e] = fg;
                if (lane == 0) { s_F[64 * 66 + e] = dd; s_vox[e] = m0 >> 3; }
            }
            __syncthreads();
            float acc[8];
            #pragma unroll
            for (int o = 0; o < 8; ++o) acc[o] = bo[obase + o];
            for (int cg2 = 0; cg2 < 64; cg2 += 4) {  // pass A compute: cols 0..64
                float f0 = s_F[(cg2 + 0) * 66 + lane];
                float f1 = s_F[(cg2 + 1) * 66 + lane];
                float f2 = s_F[(cg2 + 2) * 66 + lane];
                float f3 = s_F[(cg2 + 3) * 66 + lane];
                #pragma unroll
                for (int o = 0; o < 8; ++o) {
                    const float* wr = wo + (obase + o) * 130 + cg2;
                    acc[o] += wr[0] * f0; acc[o] += wr[1] * f1;
                    acc[o] += wr[2] * f2; acc[o] += wr[3] * f3;
                }
            }
            {
                float fd = s_F[64 * 66 + lane];
                #pragma unroll
                for (int o = 0; o < 8; ++o) acc[o] += wo[(obase + o) * 130 + 64] * fd;
            }
            __syncthreads();
            // pass B gather: cams {1,2,5}
            for (int e = wv; e < tl; e += 8) {
                float4 r0 = s_rec[2 * e + 0];
                float4 r1 = s_rec[2 * e + 1];
                int m0 = __float_as_int(r0.w), m1 = __float_as_int(r1.w);
                int ca = m0 & 7, cb = m1 & 7;
                float fg = 0.0f, dd = 0.0f;
                if (ca == 1 || ca == 2 || ca == 5) {
                    fg += gather_bilin(featT, 1, lane, ca, r0.x, r0.y);
                    dd += r0.z / 100.0f;
                }
                if (cb == 1 || cb == 2 || cb == 5) {
                    fg += gather_bilin(featT, 1, lane, cb, r1.x, r1.y);
                    dd += r1.z / 100.0f;
                }
                s_F[lane * 66 + e] = fg;
                if (lane == 0) s_F[64 * 66 + e] = dd;
            }
            __syncthreads();
            for (int cg2 = 0; cg2 < 64; cg2 += 4) {  // pass B compute: cols 65..129
                float f0 = s_F[(cg2 + 0) * 66 + lane];
                float f1 = s_F[(cg2 + 1) * 66 + lane];
                float f2 = s_F[(cg2 + 2) * 66 + lane];
                float f3 = s_F[(cg2 + 3) * 66 + lane];
                #pragma unroll
                for (int o = 0; o < 8; ++o) {
                    const float* wr = wo + (obase + o) * 130 + 65 + cg2;
                    acc[o] += wr[0] * f0; acc[o] += wr[1] * f1;
                    acc[o] += wr[2] * f2; acc[o] += wr[3] * f3;
                }
            }
            {
                float fd = s_F[64 * 66 + lane];
                #pragma unroll
                for (int o = 0; o < 8; ++o) acc[o] += wo[(obase + o) * 130 + 129] * fd;
            }
            if (lane < tl) {
                size_t col = (size_t)s_vox[lane];
                #pragma unroll
                for (int o = 0; o < 8; ++o)
                    outp[(size_t)(obase + o) * NVOX + col] = elu1(acc[o]);
            }
            __syncthreads();
        }
    }
}

// =====================================================================
// FALLBACK PATH (round-3 proven 4-kernel chain, old workspace layout)
// =====================================================================
__global__ __launch_bounds__(256) void zero_out(float4* __restrict__ p, int n4) {
    int i = blockIdx.x * 256 + threadIdx.x;
    int stride = gridDim.x * 256;
    for (; i < n4; i += stride)
        p[i] = make_float4(0.f, 0.f, 0.f, 0.f);
}

__global__ __launch_bounds__(256) void transpose_feats(const float* __restrict__ in,
                                                       float* __restrict__ out,
                                                       int* __restrict__ cnt) {
    __shared__ float tile[64 * 65];
    if (cnt && blockIdx.x == 0 && threadIdx.x < 2) cnt[threadIdx.x] = 0;
    int blk = blockIdx.x;            // 6 * 220
    int c = blk / 220;
    int p0 = (blk - c * 220) * 64;
    int tid = threadIdx.x;
    int lane = tid & 63;
    int quad = tid >> 6;
    for (int r = quad; r < 64; r += 4)
        tile[r * 65 + lane] = in[(c * 64 + r) * NPIX + p0 + lane];
    __syncthreads();
    for (int r = quad; r < 64; r += 4)
        out[((c * NPIX) + p0 + r) * 64 + lane] = tile[lane * 65 + r];
}

__global__ __launch_bounds__(256) void vox_geom(
    const float* __restrict__ mask,
    const float* __restrict__ Kg,
    const float* __restrict__ ext,
    float4* __restrict__ rec1,
    float4* __restrict__ rec2,
    int* __restrict__ cnt)
{
    __shared__ float s_ext[72];
    __shared__ float s_K[54];
    __shared__ float4 s_r1[256];
    __shared__ float4 s_r2[512];
    __shared__ int s_c1, s_c2, s_b1, s_b2;

    int tid = threadIdx.x;
    if (tid == 0) { s_c1 = 0; s_c2 = 0; }
    if (tid >= 64 && tid < 136) {
        int i = tid - 64;
        s_ext[i] = ext[(i / 12) * 16 + (i % 12)];
    }
    if (tid >= 160 && tid < 214) {
        int i = tid - 160; int cam = i / 9; int e = i - cam * 9;
        s_K[i] = Kg[cam * 16 + (e / 3) * 4 + (e % 3)];
    }
    __syncthreads();

    int n = blockIdx.x * 256 + tid;
    if (n < NVOX) {
        #pragma clang fp contract(off)
        int xi = n % 100;
        int t = n / 100;
        int yi = t % 100;
        int zi = t / 100;
        float X = -50.0f + (float)xi;
        float Y = -50.0f + (float)yi;
        float Z = -15.0f + 1.5f * (float)zi;
        int cc = 0, cam0 = 0, cam1 = 0;
        float ax = 0.f, ay = 0.f, az = 0.f, bx = 0.f, by = 0.f, bz = 0.f;
        #pragma unroll
        for (int cam = 0; cam < NC; ++cam) {
            const float* E = s_ext + cam * 12;
            const float* Kk = s_K + cam * 9;
            float vl0 = E[0]*X + E[1]*Y + E[2]*Z + E[3];
            float vl1 = E[4]*X + E[5]*Y + E[6]*Z + E[7];
            float vl2 = E[8]*X + E[9]*Y + E[10]*Z + E[11];
            float c0 = Kk[0]*vl0 + Kk[1]*vl1 + Kk[2]*vl2;
            float c1 = Kk[3]*vl0 + Kk[4]*vl1 + Kk[5]*vl2;
            float c2 = Kk[6]*vl0 + Kk[7]*vl1 + Kk[8]*vl2;
            float pz = c2 + 1e-8f;
            float px = c0 / pz;
            float py = c1 / pz;
            float gx = (px / 159.0f - 0.5f) * 2.0f;
            float gy = (py / 87.0f - 0.5f) * 2.0f;
            float x = ((gx + 1.0f) * 0.5f) * 159.0f;
            float y = ((gy + 1.0f) * 0.5f) * 87.0f;
            float xr = rintf(x), yr = rintf(y);
            bool nv = (xr >= 0.0f) && (xr <= 159.0f) && (yr >= 0.0f) && (yr <= 87.0f);
            float mval = 0.0f;
            if (nv) mval = mask[(cam * HH + (int)yr) * WW + (int)xr];
            bool ok = (mval > 0.5f) && (vl2 > 0.0f) &&
                      !((gx > 1.0f) || (gx < -1.0f) || (gy > 1.0f) || (gy < -1.0f));
            if (ok) {
                if (cc == 0) { ax = x; ay = y; az = vl2; cam0 = cam; }
                else if (cc == 1) { bx = x; by = y; bz = vl2; cam1 = cam; }
                ++cc;
            }
        }
        if (cc == 1) {
            int s = atomicAdd(&s_c1, 1);
            s_r1[s] = make_float4(ax, ay, az, __int_as_float((n << 3) | cam0));
        } else if (cc == 2) {
            int s = atomicAdd(&s_c2, 1);
            s_r2[2 * s + 0] = make_float4(ax, ay, az, __int_as_float((n << 3) | cam0));
            s_r2[2 * s + 1] = make_float4(bx, by, bz, __int_as_float((n << 3) | cam1));
        }
    }
    __syncthreads();
    if (tid == 0) {
        s_b1 = atomicAdd(cnt + 0, s_c1);
        s_b2 = atomicAdd(cnt + 1, s_c2);
    }
    __syncthreads();
    int c1 = s_c1, c2 = s_c2, b1 = s_b1, b2 = s_b2;
    for (int i = tid; i < c1; i += 256) rec1[b1 + i] = s_r1[i];
    for (int i = tid; i < 2 * c2; i += 256) rec2[2 * b2 + i] = s_r2[i];
}

__global__ __launch_bounds__(256) void vox_comp(
    const float* __restrict__ featT,
    const float* __restrict__ wno,
    const float* __restrict__ bno,
    const float* __restrict__ wo,
    const float* __restrict__ bo,
    float* __restrict__ outp,
    const float4* __restrict__ rec1,
    const float4* __restrict__ rec2,
    const int* __restrict__ cnt)
{
    __shared__ float s_F[65 * 66];
    __shared__ float4 s_rec[128];
    __shared__ int s_vox[64];

    int tid = threadIdx.x;
    int lane = tid & 63;
    int wv = tid >> 6;
    int wvu = __builtin_amdgcn_readfirstlane(wv);
    int obase = wvu * 16;

    int n1 = cnt[0], n2 = cnt[1];
    int T1 = (n1 + 63) >> 6;
    int T2 = (n2 + 63) >> 6;
    int TT = T1 + T2;

    for (int t = blockIdx.x; t < TT; t += gridDim.x) {
        if (t < T1) {
            int e0 = t << 6;
            int tl = min(64, n1 - e0);
            if (tid < tl) s_rec[tid] = rec1[e0 + tid];
            __syncthreads();
            for (int e = wv; e < tl; e += 4) {
                float4 r = s_rec[e];
                int meta = __float_as_int(r.w);
                int cam = meta & 7;
                float fv = gather_bilin(featT, 1, lane, cam, r.x, r.y);
                s_F[lane * 66 + e] = fv;
                if (lane == 0) { s_F[64 * 66 + e] = r.z / 100.0f; s_vox[e] = meta >> 3; }
            }
            __syncthreads();
            float acc[16];
            #pragma unroll
            for (int o = 0; o < 16; ++o) acc[o] = bno[obase + o];
            for (int cg2 = 0; cg2 < 64; cg2 += 4) {
                float f0 = s_F[(cg2 + 0) * 66 + lane];
                float f1 = s_F[(cg2 + 1) * 66 + lane];
                float f2 = s_F[(cg2 + 2) * 66 + lane];
                float f3 = s_F[(cg2 + 3) * 66 + lane];
                #pragma unroll
                for (int o = 0; o < 16; ++o) {
                    const float* wr = wno + (obase + o) * 65 + cg2;
                    acc[o] += wr[0] * f0; acc[o] += wr[1] * f1;
                    acc[o] += wr[2] * f2; acc[o] += wr[3] * f3;
                }
            }
            {
                float fd = s_F[64 * 66 + lane];
                #pragma unroll
                for (int o = 0; o < 16; ++o) acc[o] += wno[(obase + o) * 65 + 64] * fd;
            }
            if (lane < tl) {
                size_t col = (size_t)s_vox[lane];
                #pragma unroll
                for (int o = 0; o < 16; ++o)
                    outp[(size_t)(obase + o) * NVOX + col] = elu1(acc[o]);
            }
            __syncthreads();
        } else {
            int tt = t - T1;
            int e0 = tt << 6;
            int tl = min(64, n2 - e0);
            if (tid < 2 * tl) s_rec[tid] = rec2[2 * e0 + tid];
            __syncthreads();
            for (int e = wv; e < tl; e += 4) {
                float4 r0 = s_rec[2 * e + 0];
                float4 r1 = s_rec[2 * e + 1];
                int m0 = __float_as_int(r0.w), m1 = __float_as_int(r1.w);
                int ca = m0 & 7, cb = m1 & 7;
                float fg = 0.0f, dd = 0.0f;
                if (!(ca == 1 || ca == 2 || ca == 5)) {
                    fg += gather_bilin(featT, 1, lane, ca, r0.x, r0.y);
                    dd += r0.z / 100.0f;
                }
                if (!(cb == 1 || cb == 2 || cb == 5)) {
                    fg += gather_bilin(featT, 1, lane, cb, r1.x, r1.y);
                    dd += r1.z / 100.0f;
                }
                s_F[lane * 66 + e] = fg;
                if (lane == 0) { s_F[64 * 66 + e] = dd; s_vox[e] = m0 >> 3; }
            }
            __syncthreads();
            float acc[16];
            #pragma unroll
            for (int o = 0; o < 16; ++o) acc[o] = bo[obase + o];
            for (int cg2 = 0; cg2 < 64; cg2 += 4) {
                float f0 = s_F[(cg2 + 0) * 66 + lane];
                float f1 = s_F[(cg2 + 1) * 66 + lane];
                float f2 = s_F[(cg2 + 2) * 66 + lane];
                float f3 = s_F[(cg2 + 3) * 66 + lane];
                #pragma unroll
                for (int o = 0; o < 16; ++o) {
                    const float* wr = wo + (obase + o) * 130 + cg2;
                    acc[o] += wr[0] * f0; acc[o] += wr[1] * f1;
                    acc[o] += wr[2] * f2; acc[o] += wr[3] * f3;
                }
            }
            {
                float fd = s_F[64 * 66 + lane];
                #pragma unroll
                for (int o = 0; o < 16; ++o) acc[o] += wo[(obase + o) * 130 + 64] * fd;
            }
            __syncthreads();
            for (int e = wv; e < tl; e += 4) {
                float4 r0 = s_rec[2 * e + 0];
                float4 r1 = s_rec[2 * e + 1];
                int m0 = __float_as_int(r0.w), m1 = __float_as_int(r1.w);
                int ca = m0 & 7, cb = m1 & 7;
                float fg = 0.0f, dd = 0.0f;
                if (ca == 1 || ca == 2 || ca == 5) {
                    fg += gather_bilin(featT, 1, lane, ca, r0.x, r0.y);
                    dd += r0.z / 100.0f;
                }
                if (cb == 1 || cb == 2 || cb == 5) {
                    fg += gather_bilin(featT, 1, lane, cb, r1.x, r1.y);
                    dd += r1.z / 100.0f;
                }
                s_F[lane * 66 + e] = fg;
                if (lane == 0) s_F[64 * 66 + e] = dd;
            }
            __syncthreads();
            for (int cg2 = 0; cg2 < 64; cg2 += 4) {
                float f0 = s_F[(cg2 + 0) * 66 + lane];
                float f1 = s_F[(cg2 + 1) * 66 + lane];
                float f2 = s_F[(cg2 + 2) * 66 + lane];
                float f3 = s_F[(cg2 + 3) * 66 + lane];
                #pragma unroll
                for (int o = 0; o < 16; ++o) {
                    const float* wr = wo + (obase + o) * 130 + 65 + cg2;
                    acc[o] += wr[0] * f0; acc[o] += wr[1] * f1;
                    acc[o] += wr[2] * f2; acc[o] += wr[3] * f3;
                }
            }
            {
                float fd = s_F[64 * 66 + lane];
                #pragma unroll
                for (int o = 0; o < 16; ++o) acc[o] += wo[(obase + o) * 130 + 129] * fd;
            }
            if (lane < tl) {
                size_t col = (size_t)s_vox[lane];
                #pragma unroll
                for (int o = 0; o < 16; ++o)
                    outp[(size_t)(obase + o) * NVOX + col] = elu1(acc[o]);
            }
            __syncthreads();
        }
    }
}

extern "C" void kernel_launch(void* const* d_in, const int* in_sizes, int n_in,
                              void* d_out, int out_size, void* d_ws, size_t ws_size,
                              hipStream_t stream) {
    const float* feats = (const float*)d_in[0];
    const float* mask  = (const float*)d_in[1];
    const float* Kg    = (const float*)d_in[2];
    const float* ext   = (const float*)d_in[3];
    const float* wno   = (const float*)d_in[4];
    const float* bno   = (const float*)d_in[5];
    const float* wo    = (const float*)d_in[6];
    const float* bo    = (const float*)d_in[7];
    float* outp = (float*)d_out;
    float* featT = (float*)d_ws;

    if (ws_size >= WS_NEED) {
        // ---- preferred: 2-dispatch atomic-free compaction path ----
        int* cnt1g = (int*)((char*)d_ws + CNT1_OFF);
        int* cnt2g = (int*)((char*)d_ws + CNT2_OFF);
        float4* rec1 = (float4*)((char*)d_ws + REC1_OFF);
        float4* rec2 = (float4*)((char*)d_ws + REC2_OFF);
        vox_prep<<<NTRB + NGRP, 256, 0, stream>>>(feats, featT, mask, Kg, ext,
                                                  outp, rec1, rec2, cnt1g, cnt2g);
        vox_comp2<<<2048, 512, 0, stream>>>(featT, wno, bno, wo, bo, outp,
                                            rec1, rec2, cnt1g, cnt2g);
    } else if (ws_size >= WS_NEED_OLD) {
        // ---- fallback: round-3 proven 4-kernel chain ----
        int* cnt = (int*)((char*)d_ws + OCNT_OFF);
        float4* rec1 = (float4*)((char*)d_ws + OREC1_OFF);
        float4* rec2 = (float4*)((char*)d_ws + OREC2_OFF);
        zero_out<<<2048, 256, 0, stream>>>((float4*)d_out,
                                           (int)((size_t)VPRE * NVOX / 4));
        transpose_feats<<<NC * 220, 256, 0, stream>>>(feats, featT, cnt);
        vox_geom<<<(NVOX + 255) / 256, 256, 0, stream>>>(mask, Kg, ext,
                                                         rec1, rec2, cnt);
        vox_comp<<<2048, 256, 0, stream>>>(featT, wno, bno, wo, bo, outp,
                                           rec1, rec2, cnt);
    } else {
        zero_out<<<2048, 256, 0, stream>>>((float4*)d_out,
                                           (int)((size_t)VPRE * NVOX / 4));
    }
}

// Round 7
// 156.678 us; speedup vs baseline: 2.6510x; 2.6510x over previous
//
#include <hip/hip_runtime.h>
#include <cmath>

#define NC 6
#define CF 64
#define HH 88
#define WW 160
#define NPIX 14080     // 88*160
#define NVOX 200000
#define VPRE 64
#define NGRP 782       // ceil(200000/256)
#define NTRB 1320      // 6*220 transpose tiles

typedef unsigned int u32;

#define FEATT_BYTES  (6u * 64u * 14080u * 4u)            // 21,626,880 (256-aligned)
// ---- layout: per-group counts + fixed per-group record slots ----
#define CNT1_OFF     (FEATT_BYTES)                       // NGRP ints (pad 4096)
#define CNT2_OFF     (CNT1_OFF + 4096u)
#define REC1_OFF     (CNT2_OFF + 4096u)                  // NVOX float4 (g*256+i)
#define REC2_OFF     (REC1_OFF + (u32)NVOX * 16u)        // 2*NVOX float4 (g*512+2i+h)
#define WS_NEED      ((size_t)REC2_OFF + (size_t)NVOX * 32u)   // 31,235,072
// ---- OLD layout (fallback path, round-3 proven) ----
#define OCNT_OFF     (FEATT_BYTES)
#define OREC1_OFF    (OCNT_OFF + 256u)
#define OREC2_OFF    (OREC1_OFF + (u32)NVOX * 16u)
#define WS_NEED_OLD  ((size_t)OREC2_OFF + (size_t)NVOX * 32u)  // 31,227,136

__device__ __forceinline__ float elu1(float x) { return x > 0.0f ? x : expm1f(x); }

// bilinear gather: voxel uniform across wave, lane = channel. (fallback kernels)
__device__ __forceinline__ float gather_bilin(const float* __restrict__ fsrc, int useT,
                                              int lane, int cam, float x, float y) {
    float x0f = floorf(x), y0f = floorf(y);
    float wx1 = x - x0f, wx0 = 1.0f - wx1;
    float wy1 = y - y0f, wy0 = 1.0f - wy1;
    float x1f = x0f + 1.0f, y1f = y0f + 1.0f;
    float bx0 = (x0f >= 0.0f && x0f <= 159.0f) ? 1.0f : 0.0f;
    float bx1 = (x1f >= 0.0f && x1f <= 159.0f) ? 1.0f : 0.0f;
    float by0 = (y0f >= 0.0f && y0f <= 87.0f) ? 1.0f : 0.0f;
    float by1 = (y1f >= 0.0f && y1f <= 87.0f) ? 1.0f : 0.0f;
    int ix0 = (int)fminf(fmaxf(x0f, 0.0f), 159.0f);
    int ix1 = (int)fminf(fmaxf(x1f, 0.0f), 159.0f);
    int iy0 = (int)fminf(fmaxf(y0f, 0.0f), 87.0f);
    int iy1 = (int)fminf(fmaxf(y1f, 0.0f), 87.0f);
    int A = useT ? 64 : 1;
    int Boff = useT ? (cam * NPIX * 64 + lane) : ((cam * 64 + lane) * NPIX);
    float v00 = fsrc[(iy0 * WW + ix0) * A + Boff];
    float v01 = fsrc[(iy1 * WW + ix0) * A + Boff];
    float v10 = fsrc[(iy0 * WW + ix1) * A + Boff];
    float v11 = fsrc[(iy1 * WW + ix1) * A + Boff];
    float fv;                                        // reference corner order
    fv  = (wx0 * wy0 * bx0 * by0) * v00;
    fv += (wx0 * wy1 * bx0 * by1) * v01;
    fv += (wx1 * wy0 * bx1 * by0) * v10;
    fv += (wx1 * wy1 * bx1 * by1) * v11;
    return fv;
}

// batched gather: lane-group of 16 handles one entry, float4 = 4 channels.
// Per-channel math identical to gather_bilin (same corner order/products).
__device__ __forceinline__ float4 gather_bilin4(const float* __restrict__ fsrc,
                                                int q, int cam, float x, float y) {
    float x0f = floorf(x), y0f = floorf(y);
    float wx1 = x - x0f, wx0 = 1.0f - wx1;
    float wy1 = y - y0f, wy0 = 1.0f - wy1;
    float x1f = x0f + 1.0f, y1f = y0f + 1.0f;
    float bx0 = (x0f >= 0.0f && x0f <= 159.0f) ? 1.0f : 0.0f;
    float bx1 = (x1f >= 0.0f && x1f <= 159.0f) ? 1.0f : 0.0f;
    float by0 = (y0f >= 0.0f && y0f <= 87.0f) ? 1.0f : 0.0f;
    float by1 = (y1f >= 0.0f && y1f <= 87.0f) ? 1.0f : 0.0f;
    int ix0 = (int)fminf(fmaxf(x0f, 0.0f), 159.0f);
    int ix1 = (int)fminf(fmaxf(x1f, 0.0f), 159.0f);
    int iy0 = (int)fminf(fmaxf(y0f, 0.0f), 87.0f);
    int iy1 = (int)fminf(fmaxf(y1f, 0.0f), 87.0f);
    const float4* base = (const float4*)(fsrc) + cam * (NPIX * 16) + q;
    float4 v00 = base[(iy0 * WW + ix0) * 16];
    float4 v01 = base[(iy1 * WW + ix0) * 16];
    float4 v10 = base[(iy0 * WW + ix1) * 16];
    float4 v11 = base[(iy1 * WW + ix1) * 16];
    float w00 = wx0 * wy0 * bx0 * by0;
    float w01 = wx0 * wy1 * bx0 * by1;
    float w10 = wx1 * wy0 * bx1 * by0;
    float w11 = wx1 * wy1 * bx1 * by1;
    float4 fv;
    fv.x  = w00 * v00.x; fv.x += w01 * v01.x; fv.x += w10 * v10.x; fv.x += w11 * v11.x;
    fv.y  = w00 * v00.y; fv.y += w01 * v01.y; fv.y += w10 * v10.y; fv.y += w11 * v11.y;
    fv.z  = w00 * v00.z; fv.z += w01 * v01.z; fv.z += w10 * v10.z; fv.z += w11 * v11.z;
    fv.w  = w00 * v00.w; fv.w += w01 * v01.w; fv.w += w10 * v10.w; fv.w += w11 * v11.w;
    return fv;
}

// =====================================================================
// K1: transpose ∥ zero-output ∥ geometry (per-group slots, NO atomics).
// (unchanged from round 5 — proven)
// =====================================================================
__global__ __launch_bounds__(256) void vox_prep(
    const float* __restrict__ feats,
    float* __restrict__ featT,
    const float* __restrict__ mask,
    const float* __restrict__ Kg,
    const float* __restrict__ ext,
    float* __restrict__ outp,
    float4* __restrict__ rec1,       // NVOX slots, g*256+i
    float4* __restrict__ rec2,       // 2*NVOX slots, g*512+2i+h
    int* __restrict__ cnt1g,         // [NGRP]
    int* __restrict__ cnt2g)         // [NGRP]
{
    __shared__ __align__(16) float s_buf[4290];      // 17160 B union
    __shared__ float s_ext[72];
    __shared__ float s_K[54];
    __shared__ int s_c1, s_c2;

    int tid = threadIdx.x;
    int lane = tid & 63;
    int wv = tid >> 6;
    int bid = blockIdx.x;

    if (bid < NTRB) {
        // ---- transpose tile ----
        int c = bid / 220;
        int p0 = (bid - c * 220) * 64;
        for (int r = wv; r < 64; r += 4)
            s_buf[r * 65 + lane] = feats[(c * 64 + r) * NPIX + p0 + lane];
        __syncthreads();
        for (int r = wv; r < 64; r += 4)
            featT[((c * NPIX) + p0 + r) * 64 + lane] = s_buf[lane * 65 + r];
    } else {
        // ---- geometry group (per-group slot output) ----
        int g = bid - NTRB;
        float4* s_r1 = (float4*)s_buf;               // 256 recs (4096 B)
        float4* s_r2 = ((float4*)s_buf) + 256;       // 512 recs (8192 B)
        if (tid == 0) { s_c1 = 0; s_c2 = 0; }
        if (tid >= 64 && tid < 136) {
            int i = tid - 64;
            s_ext[i] = ext[(i / 12) * 16 + (i % 12)];
        }
        if (tid >= 160 && tid < 214) {
            int i = tid - 160; int cam = i / 9; int e = i - cam * 9;
            s_K[i] = Kg[cam * 16 + (e / 3) * 4 + (e % 3)];
        }
        __syncthreads();
        int n = g * 256 + tid;
        if (n < NVOX) {
            #pragma clang fp contract(off)
            int xi = n % 100;
            int t = n / 100;
            int yi = t % 100;
            int zi = t / 100;
            float X = -50.0f + (float)xi;
            float Y = -50.0f + (float)yi;
            float Z = -15.0f + 1.5f * (float)zi;
            int cc = 0, cam0 = 0, cam1 = 0;
            float ax = 0.f, ay = 0.f, az = 0.f, bx = 0.f, by = 0.f, bz = 0.f;
            #pragma unroll
            for (int cam = 0; cam < NC; ++cam) {
                const float* E = s_ext + cam * 12;
                const float* Kk = s_K + cam * 9;
                float vl0 = E[0]*X + E[1]*Y + E[2]*Z + E[3];
                float vl1 = E[4]*X + E[5]*Y + E[6]*Z + E[7];
                float vl2 = E[8]*X + E[9]*Y + E[10]*Z + E[11];
                float c0 = Kk[0]*vl0 + Kk[1]*vl1 + Kk[2]*vl2;
                float c1 = Kk[3]*vl0 + Kk[4]*vl1 + Kk[5]*vl2;
                float c2 = Kk[6]*vl0 + Kk[7]*vl1 + Kk[8]*vl2;
                float pz = c2 + 1e-8f;
                float px = c0 / pz;
                float py = c1 / pz;
                float gx = (px / 159.0f - 0.5f) * 2.0f;
                float gy = (py / 87.0f - 0.5f) * 2.0f;
                float x = ((gx + 1.0f) * 0.5f) * 159.0f;
                float y = ((gy + 1.0f) * 0.5f) * 87.0f;
                float xr = rintf(x), yr = rintf(y);
                bool nv = (xr >= 0.0f) && (xr <= 159.0f) && (yr >= 0.0f) && (yr <= 87.0f);
                float mval = 0.0f;
                if (nv) mval = mask[(cam * HH + (int)yr) * WW + (int)xr];
                bool ok = (mval > 0.5f) && (vl2 > 0.0f) &&
                          !((gx > 1.0f) || (gx < -1.0f) || (gy > 1.0f) || (gy < -1.0f));
                if (ok) {
                    if (cc == 0) { ax = x; ay = y; az = vl2; cam0 = cam; }
                    else if (cc == 1) { bx = x; by = y; bz = vl2; cam1 = cam; }
                    ++cc;
                }
            }
            if (cc == 1) {
                int s = atomicAdd(&s_c1, 1);
                s_r1[s] = make_float4(ax, ay, az, __int_as_float((n << 3) | cam0));
            } else if (cc == 2) {
                int s = atomicAdd(&s_c2, 1);
                s_r2[2 * s + 0] = make_float4(ax, ay, az, __int_as_float((n << 3) | cam0));
                s_r2[2 * s + 1] = make_float4(bx, by, bz, __int_as_float((n << 3) | cam1));
            }
        }
        __syncthreads();
        int c1 = s_c1, c2 = s_c2;
        if (tid == 0) { cnt1g[g] = c1; cnt2g[g] = c2; }
        for (int i = tid; i < c1; i += 256) rec1[g * 256 + i] = s_r1[i];
        for (int i = tid; i < 2 * c2; i += 256) rec2[g * 512 + i] = s_r2[i];
    }

    // ---- grid-stride zero of the output window (independent of above) ----
    {
        float4* o4 = (float4*)outp;
        const int n4 = VPRE * NVOX / 4;
        const int stride = (NTRB + NGRP) * 256;
        for (int i = bid * 256 + tid; i < n4; i += stride)
            o4[i] = make_float4(0.f, 0.f, 0.f, 0.f);
    }
}

// inclusive prefix over NGRP counts (256-thread version, round-5 proven).
__device__ __forceinline__ void scan_counts(const int* __restrict__ cg,
                                            int* s_scr, int* s_P, int tid) {
    int base = tid * 4;
    int v0 = (base + 0 < NGRP) ? cg[base + 0] : 0;
    int v1 = (base + 1 < NGRP) ? cg[base + 1] : 0;
    int v2 = (base + 2 < NGRP) ? cg[base + 2] : 0;
    int v3 = (base + 3 < NGRP) ? cg[base + 3] : 0;
    int s0 = v0, s1 = s0 + v1, s2 = s1 + v2, s3 = s2 + v3;
    s_scr[tid] = s3;
    __syncthreads();
    for (int off = 1; off < 256; off <<= 1) {
        int x = s_scr[tid];
        int y = (tid >= off) ? s_scr[tid - off] : 0;
        __syncthreads();
        s_scr[tid] = x + y;
        __syncthreads();
    }
    int excl = (tid > 0) ? s_scr[tid - 1] : 0;
    if (base + 0 < NGRP) s_P[base + 0] = excl + s0;
    if (base + 1 < NGRP) s_P[base + 1] = excl + s1;
    if (base + 2 < NGRP) s_P[base + 2] = excl + s2;
    if (base + 3 < NGRP) s_P[base + 3] = excl + s3;
    __syncthreads();
}

__device__ __forceinline__ int bsearch_grp(const int* __restrict__ P, int k) {
    int lo = 0, hi = NGRP - 1;
    while (lo < hi) { int mid = (lo + hi) >> 1; if (P[mid] > k) hi = mid; else lo = mid + 1; }
    return lo;
}

// =====================================================================
// K2: comp over virtually-compacted 64-entry tiles. 256 threads = 4
// waves x 16 output rows (round-5 proven shape). ONLY change vs r5:
// gather phases batch 4 entries/wave-iteration via float4 channel loads
// (serial load chain 16 -> 4 batches), #pragma unroll 1 for VGPR.
// =====================================================================
__global__ __launch_bounds__(256) void vox_comp2(
    const float* __restrict__ featT,
    const float* __restrict__ wno,   // [64][65]
    const float* __restrict__ bno,   // [64]
    const float* __restrict__ wo,    // [64][130]
    const float* __restrict__ bo,    // [64]
    float* __restrict__ outp,        // [64][200000]
    const float4* __restrict__ rec1,
    const float4* __restrict__ rec2,
    const int* __restrict__ cnt1g,
    const int* __restrict__ cnt2g)
{
    __shared__ __align__(16) float s_F[65 * 66];
    __shared__ float4 s_rec[128];
    __shared__ int s_vox[64];
    __shared__ int s_P1[NGRP];
    __shared__ int s_P2[NGRP];

    int tid = threadIdx.x;
    int lane = tid & 63;
    int wv = tid >> 6;                               // 0..3
    int wvu = __builtin_amdgcn_readfirstlane(wv);
    int obase = wvu * 16;
    int q = lane & 15;                               // channel quad
    int j4 = lane >> 4;                              // entry subgroup 0..3

    scan_counts(cnt1g, (int*)s_F, s_P1, tid);
    scan_counts(cnt2g, (int*)s_F, s_P2, tid);
    int n1 = s_P1[NGRP - 1], n2 = s_P2[NGRP - 1];
    int T1 = (n1 + 63) >> 6;
    int T2 = (n2 + 63) >> 6;
    int TT = T1 + T2;

    for (int t = blockIdx.x; t < TT; t += gridDim.x) {
        if (t < T1) {
            // ---------------- count == 1 tile ----------------
            int e0 = t << 6;
            int tl = min(64, n1 - e0);
            if (tid < tl) {
                int k = e0 + tid;
                int g = bsearch_grp(s_P1, k);
                int l = k - ((g > 0) ? s_P1[g - 1] : 0);
                s_rec[tid] = rec1[g * 256 + l];
            }
            __syncthreads();
            #pragma unroll 1
            for (int u = 0; u < 4; ++u) {
                int e = wv + 4 * (4 * u + j4);        // wave wv covers e ≡ wv (mod 4)
                if (e < tl) {
                    float4 r = s_rec[e];
                    int meta = __float_as_int(r.w);
                    int cam = meta & 7;
                    float4 fv = gather_bilin4(featT, q, cam, r.x, r.y);
                    s_F[(4 * q + 0) * 66 + e] = fv.x;
                    s_F[(4 * q + 1) * 66 + e] = fv.y;
                    s_F[(4 * q + 2) * 66 + e] = fv.z;
                    s_F[(4 * q + 3) * 66 + e] = fv.w;
                    if (q == 0) { s_F[64 * 66 + e] = r.z / 100.0f; s_vox[e] = meta >> 3; }
                }
            }
            __syncthreads();
            float acc[16];
            #pragma unroll
            for (int o = 0; o < 16; ++o) acc[o] = bno[obase + o];
            for (int cg2 = 0; cg2 < 64; cg2 += 4) {
                float f0 = s_F[(cg2 + 0) * 66 + lane];
                float f1 = s_F[(cg2 + 1) * 66 + lane];
                float f2 = s_F[(cg2 + 2) * 66 + lane];
                float f3 = s_F[(cg2 + 3) * 66 + lane];
                #pragma unroll
                for (int o = 0; o < 16; ++o) {
                    const float* wr = wno + (obase + o) * 65 + cg2;
                    acc[o] += wr[0] * f0; acc[o] += wr[1] * f1;
                    acc[o] += wr[2] * f2; acc[o] += wr[3] * f3;
                }
            }
            {
                float fd = s_F[64 * 66 + lane];
                #pragma unroll
                for (int o = 0; o < 16; ++o) acc[o] += wno[(obase + o) * 65 + 64] * fd;
            }
            if (lane < tl) {
                size_t col = (size_t)s_vox[lane];
                #pragma unroll
                for (int o = 0; o < 16; ++o)
                    outp[(size_t)(obase + o) * NVOX + col] = elu1(acc[o]);
            }
            __syncthreads();
        } else {
            // ---------------- count == 2 tile: two passes ----------------
            int tt = t - T1;
            int e0 = tt << 6;
            int tl = min(64, n2 - e0);
            if (tid < 2 * tl) {
                int p = tid >> 1, h = tid & 1;
                int k = e0 + p;
                int g = bsearch_grp(s_P2, k);
                int l = k - ((g > 0) ? s_P2[g - 1] : 0);
                s_rec[tid] = rec2[g * 512 + 2 * l + h];
            }
            __syncthreads();
            // pass A gather: cams {0,3,4}
            #pragma unroll 1
            for (int u = 0; u < 4; ++u) {
                int e = wv + 4 * (4 * u + j4);
                if (e < tl) {
                    float4 r0 = s_rec[2 * e + 0];
                    float4 r1 = s_rec[2 * e + 1];
                    int m0 = __float_as_int(r0.w), m1 = __float_as_int(r1.w);
                    int ca = m0 & 7, cb = m1 & 7;
                    float4 fg = make_float4(0.f, 0.f, 0.f, 0.f);
                    float dd = 0.0f;
                    if (!(ca == 1 || ca == 2 || ca == 5)) {
                        float4 g = gather_bilin4(featT, q, ca, r0.x, r0.y);
                        fg.x += g.x; fg.y += g.y; fg.z += g.z; fg.w += g.w;
                        dd += r0.z / 100.0f;
                    }
                    if (!(cb == 1 || cb == 2 || cb == 5)) {
                        float4 g = gather_bilin4(featT, q, cb, r1.x, r1.y);
                        fg.x += g.x; fg.y += g.y; fg.z += g.z; fg.w += g.w;
                        dd += r1.z / 100.0f;
                    }
                    s_F[(4 * q + 0) * 66 + e] = fg.x;
                    s_F[(4 * q + 1) * 66 + e] = fg.y;
                    s_F[(4 * q + 2) * 66 + e] = fg.z;
                    s_F[(4 * q + 3) * 66 + e] = fg.w;
                    if (q == 0) { s_F[64 * 66 + e] = dd; s_vox[e] = m0 >> 3; }
                }
            }
            __syncthreads();
            float acc[16];
            #pragma unroll
            for (int o = 0; o < 16; ++o) acc[o] = bo[obase + o];
            for (int cg2 = 0; cg2 < 64; cg2 += 4) {  // pass A compute: cols 0..64
                float f0 = s_F[(cg2 + 0) * 66 + lane];
                float f1 = s_F[(cg2 + 1) * 66 + lane];
                float f2 = s_F[(cg2 + 2) * 66 + lane];
                float f3 = s_F[(cg2 + 3) * 66 + lane];
                #pragma unroll
                for (int o = 0; o < 16; ++o) {
                    const float* wr = wo + (obase + o) * 130 + cg2;
                    acc[o] += wr[0] * f0; acc[o] += wr[1] * f1;
                    acc[o] += wr[2] * f2; acc[o] += wr[3] * f3;
                }
            }
            {
                float fd = s_F[64 * 66 + lane];
                #pragma unroll
                for (int o = 0; o < 16; ++o) acc[o] += wo[(obase + o) * 130 + 64] * fd;
            }
            __syncthreads();
            // pass B gather: cams {1,2,5}
            #pragma unroll 1
            for (int u = 0; u < 4; ++u) {
                int e = wv + 4 * (4 * u + j4);
                if (e < tl) {
                    float4 r0 = s_rec[2 * e + 0];
                    float4 r1 = s_rec[2 * e + 1];
                    int m0 = __float_as_int(r0.w), m1 = __float_as_int(r1.w);
                    int ca = m0 & 7, cb = m1 & 7;
                    float4 fg = make_float4(0.f, 0.f, 0.f, 0.f);
                    float dd = 0.0f;
                    if (ca == 1 || ca == 2 || ca == 5) {
                        float4 g = gather_bilin4(featT, q, ca, r0.x, r0.y);
                        fg.x += g.x; fg.y += g.y; fg.z += g.z; fg.w += g.w;
                        dd += r0.z / 100.0f;
                    }
                    if (cb == 1 || cb == 2 || cb == 5) {
                        float4 g = gather_bilin4(featT, q, cb, r1.x, r1.y);
                        fg.x += g.x; fg.y += g.y; fg.z += g.z; fg.w += g.w;
                        dd += r1.z / 100.0f;
                    }
                    s_F[(4 * q + 0) * 66 + e] = fg.x;
                    s_F[(4 * q + 1) * 66 + e] = fg.y;
                    s_F[(4 * q + 2) * 66 + e] = fg.z;
                    s_F[(4 * q + 3) * 66 + e] = fg.w;
                    if (q == 0) s_F[64 * 66 + e] = dd;
                }
            }
            __syncthreads();
            for (int cg2 = 0; cg2 < 64; cg2 += 4) {  // pass B compute: cols 65..129
                float f0 = s_F[(cg2 + 0) * 66 + lane];
                float f1 = s_F[(cg2 + 1) * 66 + lane];
                float f2 = s_F[(cg2 + 2) * 66 + lane];
                float f3 = s_F[(cg2 + 3) * 66 + lane];
                #pragma unroll
                for (int o = 0; o < 16; ++o) {
                    const float* wr = wo + (obase + o) * 130 + 65 + cg2;
                    acc[o] += wr[0] * f0; acc[o] += wr[1] * f1;
                    acc[o] += wr[2] * f2; acc[o] += wr[3] * f3;
                }
            }
            {
                float fd = s_F[64 * 66 + lane];
                #pragma unroll
                for (int o = 0; o < 16; ++o) acc[o] += wo[(obase + o) * 130 + 129] * fd;
            }
            if (lane < tl) {
                size_t col = (size_t)s_vox[lane];
                #pragma unroll
                for (int o = 0; o < 16; ++o)
                    outp[(size_t)(obase + o) * NVOX + col] = elu1(acc[o]);
            }
            __syncthreads();
        }
    }
}

// =====================================================================
// FALLBACK PATH (round-3 proven 4-kernel chain, old workspace layout)
// =====================================================================
__global__ __launch_bounds__(256) void zero_out(float4* __restrict__ p, int n4) {
    int i = blockIdx.x * 256 + threadIdx.x;
    int stride = gridDim.x * 256;
    for (; i < n4; i += stride)
        p[i] = make_float4(0.f, 0.f, 0.f, 0.f);
}

__global__ __launch_bounds__(256) void transpose_feats(const float* __restrict__ in,
                                                       float* __restrict__ out,
                                                       int* __restrict__ cnt) {
    __shared__ float tile[64 * 65];
    if (cnt && blockIdx.x == 0 && threadIdx.x < 2) cnt[threadIdx.x] = 0;
    int blk = blockIdx.x;            // 6 * 220
    int c = blk / 220;
    int p0 = (blk - c * 220) * 64;
    int tid = threadIdx.x;
    int lane = tid & 63;
    int quad = tid >> 6;
    for (int r = quad; r < 64; r += 4)
        tile[r * 65 + lane] = in[(c * 64 + r) * NPIX + p0 + lane];
    __syncthreads();
    for (int r = quad; r < 64; r += 4)
        out[((c * NPIX) + p0 + r) * 64 + lane] = tile[lane * 65 + r];
}

__global__ __launch_bounds__(256) void vox_geom(
    const float* __restrict__ mask,
    const float* __restrict__ Kg,
    const float* __restrict__ ext,
    float4* __restrict__ rec1,
    float4* __restrict__ rec2,
    int* __restrict__ cnt)
{
    __shared__ float s_ext[72];
    __shared__ float s_K[54];
    __shared__ float4 s_r1[256];
    __shared__ float4 s_r2[512];
    __shared__ int s_c1, s_c2, s_b1, s_b2;

    int tid = threadIdx.x;
    if (tid == 0) { s_c1 = 0; s_c2 = 0; }
    if (tid >= 64 && tid < 136) {
        int i = tid - 64;
        s_ext[i] = ext[(i / 12) * 16 + (i % 12)];
    }
    if (tid >= 160 && tid < 214) {
        int i = tid - 160; int cam = i / 9; int e = i - cam * 9;
        s_K[i] = Kg[cam * 16 + (e / 3) * 4 + (e % 3)];
    }
    __syncthreads();

    int n = blockIdx.x * 256 + tid;
    if (n < NVOX) {
        #pragma clang fp contract(off)
        int xi = n % 100;
        int t = n / 100;
        int yi = t % 100;
        int zi = t / 100;
        float X = -50.0f + (float)xi;
        float Y = -50.0f + (float)yi;
        float Z = -15.0f + 1.5f * (float)zi;
        int cc = 0, cam0 = 0, cam1 = 0;
        float ax = 0.f, ay = 0.f, az = 0.f, bx = 0.f, by = 0.f, bz = 0.f;
        #pragma unroll
        for (int cam = 0; cam < NC; ++cam) {
            const float* E = s_ext + cam * 12;
            const float* Kk = s_K + cam * 9;
            float vl0 = E[0]*X + E[1]*Y + E[2]*Z + E[3];
            float vl1 = E[4]*X + E[5]*Y + E[6]*Z + E[7];
            float vl2 = E[8]*X + E[9]*Y + E[10]*Z + E[11];
            float c0 = Kk[0]*vl0 + Kk[1]*vl1 + Kk[2]*vl2;
            float c1 = Kk[3]*vl0 + Kk[4]*vl1 + Kk[5]*vl2;
            float c2 = Kk[6]*vl0 + Kk[7]*vl1 + Kk[8]*vl2;
            float pz = c2 + 1e-8f;
            float px = c0 / pz;
            float py = c1 / pz;
            float gx = (px / 159.0f - 0.5f) * 2.0f;
            float gy = (py / 87.0f - 0.5f) * 2.0f;
            float x = ((gx + 1.0f) * 0.5f) * 159.0f;
            float y = ((gy + 1.0f) * 0.5f) * 87.0f;
            float xr = rintf(x), yr = rintf(y);
            bool nv = (xr >= 0.0f) && (xr <= 159.0f) && (yr >= 0.0f) && (yr <= 87.0f);
            float mval = 0.0f;
            if (nv) mval = mask[(cam * HH + (int)yr) * WW + (int)xr];
            bool ok = (mval > 0.5f) && (vl2 > 0.0f) &&
                      !((gx > 1.0f) || (gx < -1.0f) || (gy > 1.0f) || (gy < -1.0f));
            if (ok) {
                if (cc == 0) { ax = x; ay = y; az = vl2; cam0 = cam; }
                else if (cc == 1) { bx = x; by = y; bz = vl2; cam1 = cam; }
                ++cc;
            }
        }
        if (cc == 1) {
            int s = atomicAdd(&s_c1, 1);
            s_r1[s] = make_float4(ax, ay, az, __int_as_float((n << 3) | cam0));
        } else if (cc == 2) {
            int s = atomicAdd(&s_c2, 1);
            s_r2[2 * s + 0] = make_float4(ax, ay, az, __int_as_float((n << 3) | cam0));
            s_r2[2 * s + 1] = make_float4(bx, by, bz, __int_as_float((n << 3) | cam1));
        }
    }
    __syncthreads();
    if (tid == 0) {
        s_b1 = atomicAdd(cnt + 0, s_c1);
        s_b2 = atomicAdd(cnt + 1, s_c2);
    }
    __syncthreads();
    int c1 = s_c1, c2 = s_c2, b1 = s_b1, b2 = s_b2;
    for (int i = tid; i < c1; i += 256) rec1[b1 + i] = s_r1[i];
    for (int i = tid; i < 2 * c2; i += 256) rec2[2 * b2 + i] = s_r2[i];
}

__global__ __launch_bounds__(256) void vox_comp(
    const float* __restrict__ featT,
    const float* __restrict__ wno,
    const float* __restrict__ bno,
    const float* __restrict__ wo,
    const float* __restrict__ bo,
    float* __restrict__ outp,
    const float4* __restrict__ rec1,
    const float4* __restrict__ rec2,
    const int* __restrict__ cnt)
{
    __shared__ float s_F[65 * 66];
    __shared__ float4 s_rec[128];
    __shared__ int s_vox[64];

    int tid = threadIdx.x;
    int lane = tid & 63;
    int wv = tid >> 6;
    int wvu = __builtin_amdgcn_readfirstlane(wv);
    int obase = wvu * 16;

    int n1 = cnt[0], n2 = cnt[1];
    int T1 = (n1 + 63) >> 6;
    int T2 = (n2 + 63) >> 6;
    int TT = T1 + T2;

    for (int t = blockIdx.x; t < TT; t += gridDim.x) {
        if (t < T1) {
            int e0 = t << 6;
            int tl = min(64, n1 - e0);
            if (tid < tl) s_rec[tid] = rec1[e0 + tid];
            __syncthreads();
            for (int e = wv; e < tl; e += 4) {
                float4 r = s_rec[e];
                int meta = __float_as_int(r.w);
                int cam = meta & 7;
                float fv = gather_bilin(featT, 1, lane, cam, r.x, r.y);
                s_F[lane * 66 + e] = fv;
                if (lane == 0) { s_F[64 * 66 + e] = r.z / 100.0f; s_vox[e] = meta >> 3; }
            }
            __syncthreads();
            float acc[16];
            #pragma unroll
            for (int o = 0; o < 16; ++o) acc[o] = bno[obase + o];
            for (int cg2 = 0; cg2 < 64; cg2 += 4) {
                float f0 = s_F[(cg2 + 0) * 66 + lane];
                float f1 = s_F[(cg2 + 1) * 66 + lane];
                float f2 = s_F[(cg2 + 2) * 66 + lane];
                float f3 = s_F[(cg2 + 3) * 66 + lane];
                #pragma unroll
                for (int o = 0; o < 16; ++o) {
                    const float* wr = wno + (obase + o) * 65 + cg2;
                    acc[o] += wr[0] * f0; acc[o] += wr[1] * f1;
                    acc[o] += wr[2] * f2; acc[o] += wr[3] * f3;
                }
            }
            {
                float fd = s_F[64 * 66 + lane];
                #pragma unroll
                for (int o = 0; o < 16; ++o) acc[o] += wno[(obase + o) * 65 + 64] * fd;
            }
            if (lane < tl) {
                size_t col = (size_t)s_vox[lane];
                #pragma unroll
                for (int o = 0; o < 16; ++o)
                    outp[(size_t)(obase + o) * NVOX + col] = elu1(acc[o]);
            }
            __syncthreads();
        } else {
            int tt = t - T1;
            int e0 = tt << 6;
            int tl = min(64, n2 - e0);
            if (tid < 2 * tl) s_rec[tid] = rec2[2 * e0 + tid];
            __syncthreads();
            for (int e = wv; e < tl; e += 4) {
                float4 r0 = s_rec[2 * e + 0];
                float4 r1 = s_rec[2 * e + 1];
                int m0 = __float_as_int(r0.w), m1 = __float_as_int(r1.w);
                int ca = m0 & 7, cb = m1 & 7;
                float fg = 0.0f, dd = 0.0f;
                if (!(ca == 1 || ca == 2 || ca == 5)) {
                    fg += gather_bilin(featT, 1, lane, ca, r0.x, r0.y);
                    dd += r0.z / 100.0f;
                }
                if (!(cb == 1 || cb == 2 || cb == 5)) {
                    fg += gather_bilin(featT, 1, lane, cb, r1.x, r1.y);
                    dd += r1.z / 100.0f;
                }
                s_F[lane * 66 + e] = fg;
                if (lane == 0) { s_F[64 * 66 + e] = dd; s_vox[e] = m0 >> 3; }
            }
            __syncthreads();
            float acc[16];
            #pragma unroll
            for (int o = 0; o < 16; ++o) acc[o] = bo[obase + o];
            for (int cg2 = 0; cg2 < 64; cg2 += 4) {
                float f0 = s_F[(cg2 + 0) * 66 + lane];
                float f1 = s_F[(cg2 + 1) * 66 + lane];
                float f2 = s_F[(cg2 + 2) * 66 + lane];
                float f3 = s_F[(cg2 + 3) * 66 + lane];
                #pragma unroll
                for (int o = 0; o < 16; ++o) {
                    const float* wr = wo + (obase + o) * 130 + cg2;
                    acc[o] += wr[0] * f0; acc[o] += wr[1] * f1;
                    acc[o] += wr[2] * f2; acc[o] += wr[3] * f3;
                }
            }
            {
                float fd = s_F[64 * 66 + lane];
                #pragma unroll
                for (int o = 0; o < 16; ++o) acc[o] += wo[(obase + o) * 130 + 64] * fd;
            }
            __syncthreads();
            for (int e = wv; e < tl; e += 4) {
                float4 r0 = s_rec[2 * e + 0];
                float4 r1 = s_rec[2 * e + 1];
                int m0 = __float_as_int(r0.w), m1 = __float_as_int(r1.w);
                int ca = m0 & 7, cb = m1 & 7;
                float fg = 0.0f, dd = 0.0f;
                if (ca == 1 || ca == 2 || ca == 5) {
                    fg += gather_bilin(featT, 1, lane, ca, r0.x, r0.y);
                    dd += r0.z / 100.0f;
                }
                if (cb == 1 || cb == 2 || cb == 5) {
                    fg += gather_bilin(featT, 1, lane, cb, r1.x, r1.y);
                    dd += r1.z / 100.0f;
                }
                s_F[lane * 66 + e] = fg;
                if (lane == 0) s_F[64 * 66 + e] = dd;
            }
            __syncthreads();
            for (int cg2 = 0; cg2 < 64; cg2 += 4) {
                float f0 = s_F[(cg2 + 0) * 66 + lane];
                float f1 = s_F[(cg2 + 1) * 66 + lane];
                float f2 = s_F[(cg2 + 2) * 66 + lane];
                float f3 = s_F[(cg2 + 3) * 66 + lane];
                #pragma unroll
                for (int o = 0; o < 16; ++o) {
                    const float* wr = wo + (obase + o) * 130 + 65 + cg2;
                    acc[o] += wr[0] * f0; acc[o] += wr[1] * f1;
                    acc[o] += wr[2] * f2; acc[o] += wr[3] * f3;
                }
            }
            {
                float fd = s_F[64 * 66 + lane];
                #pragma unroll
                for (int o = 0; o < 16; ++o) acc[o] += wo[(obase + o) * 130 + 129] * fd;
            }
            if (lane < tl) {
                size_t col = (size_t)s_vox[lane];
                #pragma unroll
                for (int o = 0; o < 16; ++o)
                    outp[(size_t)(obase + o) * NVOX + col] = elu1(acc[o]);
            }
            __syncthreads();
        }
    }
}

extern "C" void kernel_launch(void* const* d_in, const int* in_sizes, int n_in,
                              void* d_out, int out_size, void* d_ws, size_t ws_size,
                              hipStream_t stream) {
    const float* feats = (const float*)d_in[0];
    const float* mask  = (const float*)d_in[1];
    const float* Kg    = (const float*)d_in[2];
    const float* ext   = (const float*)d_in[3];
    const float* wno   = (const float*)d_in[4];
    const float* bno   = (const float*)d_in[5];
    const float* wo    = (const float*)d_in[6];
    const float* bo    = (const float*)d_in[7];
    float* outp = (float*)d_out;
    float* featT = (float*)d_ws;

    if (ws_size >= WS_NEED) {
        // ---- preferred: 2-dispatch atomic-free compaction path ----
        int* cnt1g = (int*)((char*)d_ws + CNT1_OFF);
        int* cnt2g = (int*)((char*)d_ws + CNT2_OFF);
        float4* rec1 = (float4*)((char*)d_ws + REC1_OFF);
        float4* rec2 = (float4*)((char*)d_ws + REC2_OFF);
        vox_prep<<<NTRB + NGRP, 256, 0, stream>>>(feats, featT, mask, Kg, ext,
                                                  outp, rec1, rec2, cnt1g, cnt2g);
        vox_comp2<<<2048, 256, 0, stream>>>(featT, wno, bno, wo, bo, outp,
                                            rec1, rec2, cnt1g, cnt2g);
    } else if (ws_size >= WS_NEED_OLD) {
        // ---- fallback: round-3 proven 4-kernel chain ----
        int* cnt = (int*)((char*)d_ws + OCNT_OFF);
        float4* rec1 = (float4*)((char*)d_ws + OREC1_OFF);
        float4* rec2 = (float4*)((char*)d_ws + OREC2_OFF);
        zero_out<<<2048, 256, 0, stream>>>((float4*)d_out,
                                           (int)((size_t)VPRE * NVOX / 4));
        transpose_feats<<<NC * 220, 256, 0, stream>>>(feats, featT, cnt);
        vox_geom<<<(NVOX + 255) / 256, 256, 0, stream>>>(mask, Kg, ext,
                                                         rec1, rec2, cnt);
        vox_comp<<<2048, 256, 0, stream>>>(featT, wno, bno, wo, bo, outp,
                                           rec1, rec2, cnt);
    } else {
        zero_out<<<2048, 256, 0, stream>>>((float4*)d_out,
                                           (int)((size_t)VPRE * NVOX / 4));
    }
}

// Round 8
// 147.666 us; speedup vs baseline: 2.8128x; 1.0610x over previous
//
#include <hip/hip_runtime.h>
#include <cmath>

#define NC 6
#define CF 64
#define HH 88
#define WW 160
#define NPIX 14080     // 88*160
#define NVOX 200000
#define VPRE 64
#define NGRP 782       // ceil(200000/256)
#define NTRB 1320      // 6*220 transpose tiles

typedef unsigned int u32;

#define FEATT_BYTES  (6u * 64u * 14080u * 4u)            // 21,626,880 (256-aligned)
// ---- layout: per-group counts + fixed per-group record slots ----
#define CNT1_OFF     (FEATT_BYTES)                       // NGRP ints (pad 4096)
#define CNT2_OFF     (CNT1_OFF + 4096u)
#define REC1_OFF     (CNT2_OFF + 4096u)                  // NVOX float4 (g*256+i)
#define REC2_OFF     (REC1_OFF + (u32)NVOX * 16u)        // 2*NVOX float4 (g*512+2i+h)
#define WS_NEED      ((size_t)REC2_OFF + (size_t)NVOX * 32u)   // 31,235,072
// ---- OLD layout (fallback path, round-3 proven) ----
#define OCNT_OFF     (FEATT_BYTES)
#define OREC1_OFF    (OCNT_OFF + 256u)
#define OREC2_OFF    (OREC1_OFF + (u32)NVOX * 16u)
#define WS_NEED_OLD  ((size_t)OREC2_OFF + (size_t)NVOX * 32u)  // 31,227,136

__device__ __forceinline__ float elu1(float x) { return x > 0.0f ? x : expm1f(x); }

// bilinear gather: voxel uniform across wave, lane = channel. (fallback kernels)
__device__ __forceinline__ float gather_bilin(const float* __restrict__ fsrc, int useT,
                                              int lane, int cam, float x, float y) {
    float x0f = floorf(x), y0f = floorf(y);
    float wx1 = x - x0f, wx0 = 1.0f - wx1;
    float wy1 = y - y0f, wy0 = 1.0f - wy1;
    float x1f = x0f + 1.0f, y1f = y0f + 1.0f;
    float bx0 = (x0f >= 0.0f && x0f <= 159.0f) ? 1.0f : 0.0f;
    float bx1 = (x1f >= 0.0f && x1f <= 159.0f) ? 1.0f : 0.0f;
    float by0 = (y0f >= 0.0f && y0f <= 87.0f) ? 1.0f : 0.0f;
    float by1 = (y1f >= 0.0f && y1f <= 87.0f) ? 1.0f : 0.0f;
    int ix0 = (int)fminf(fmaxf(x0f, 0.0f), 159.0f);
    int ix1 = (int)fminf(fmaxf(x1f, 0.0f), 159.0f);
    int iy0 = (int)fminf(fmaxf(y0f, 0.0f), 87.0f);
    int iy1 = (int)fminf(fmaxf(y1f, 0.0f), 87.0f);
    int A = useT ? 64 : 1;
    int Boff = useT ? (cam * NPIX * 64 + lane) : ((cam * 64 + lane) * NPIX);
    float v00 = fsrc[(iy0 * WW + ix0) * A + Boff];
    float v01 = fsrc[(iy1 * WW + ix0) * A + Boff];
    float v10 = fsrc[(iy0 * WW + ix1) * A + Boff];
    float v11 = fsrc[(iy1 * WW + ix1) * A + Boff];
    float fv;                                        // reference corner order
    fv  = (wx0 * wy0 * bx0 * by0) * v00;
    fv += (wx0 * wy1 * bx0 * by1) * v01;
    fv += (wx1 * wy0 * bx1 * by0) * v10;
    fv += (wx1 * wy1 * bx1 * by1) * v11;
    return fv;
}

// 8-channel batched gather: lane-octet handles channels 8q8..8q8+7 via
// two float4 loads per corner. Per-channel math identical to gather_bilin.
__device__ __forceinline__ void gather_bilin8(const float* __restrict__ fsrc,
                                              int q8, int cam, float x, float y,
                                              float4& fa, float4& fb) {
    float x0f = floorf(x), y0f = floorf(y);
    float wx1 = x - x0f, wx0 = 1.0f - wx1;
    float wy1 = y - y0f, wy0 = 1.0f - wy1;
    float x1f = x0f + 1.0f, y1f = y0f + 1.0f;
    float bx0 = (x0f >= 0.0f && x0f <= 159.0f) ? 1.0f : 0.0f;
    float bx1 = (x1f >= 0.0f && x1f <= 159.0f) ? 1.0f : 0.0f;
    float by0 = (y0f >= 0.0f && y0f <= 87.0f) ? 1.0f : 0.0f;
    float by1 = (y1f >= 0.0f && y1f <= 87.0f) ? 1.0f : 0.0f;
    int ix0 = (int)fminf(fmaxf(x0f, 0.0f), 159.0f);
    int ix1 = (int)fminf(fmaxf(x1f, 0.0f), 159.0f);
    int iy0 = (int)fminf(fmaxf(y0f, 0.0f), 87.0f);
    int iy1 = (int)fminf(fmaxf(y1f, 0.0f), 87.0f);
    const float4* base = (const float4*)(fsrc) + cam * (NPIX * 16) + 2 * q8;
    int p00 = (iy0 * WW + ix0) * 16;
    int p01 = (iy1 * WW + ix0) * 16;
    int p10 = (iy0 * WW + ix1) * 16;
    int p11 = (iy1 * WW + ix1) * 16;
    float4 a00 = base[p00], b00 = base[p00 + 1];
    float4 a01 = base[p01], b01 = base[p01 + 1];
    float4 a10 = base[p10], b10 = base[p10 + 1];
    float4 a11 = base[p11], b11 = base[p11 + 1];
    float w00 = wx0 * wy0 * bx0 * by0;
    float w01 = wx0 * wy1 * bx0 * by1;
    float w10 = wx1 * wy0 * bx1 * by0;
    float w11 = wx1 * wy1 * bx1 * by1;
    fa.x  = w00 * a00.x; fa.x += w01 * a01.x; fa.x += w10 * a10.x; fa.x += w11 * a11.x;
    fa.y  = w00 * a00.y; fa.y += w01 * a01.y; fa.y += w10 * a10.y; fa.y += w11 * a11.y;
    fa.z  = w00 * a00.z; fa.z += w01 * a01.z; fa.z += w10 * a10.z; fa.z += w11 * a11.z;
    fa.w  = w00 * a00.w; fa.w += w01 * a01.w; fa.w += w10 * a10.w; fa.w += w11 * a11.w;
    fb.x  = w00 * b00.x; fb.x += w01 * b01.x; fb.x += w10 * b10.x; fb.x += w11 * b11.x;
    fb.y  = w00 * b00.y; fb.y += w01 * b01.y; fb.y += w10 * b10.y; fb.y += w11 * b11.y;
    fb.z  = w00 * b00.z; fb.z += w01 * b01.z; fb.z += w10 * b10.z; fb.z += w11 * b11.z;
    fb.w  = w00 * b00.w; fb.w += w01 * b01.w; fb.w += w10 * b10.w; fb.w += w11 * b11.w;
}

// =====================================================================
// K1: transpose ∥ zero-output ∥ geometry (per-group slots, NO atomics).
// (unchanged from round 5 — proven)
// =====================================================================
__global__ __launch_bounds__(256) void vox_prep(
    const float* __restrict__ feats,
    float* __restrict__ featT,
    const float* __restrict__ mask,
    const float* __restrict__ Kg,
    const float* __restrict__ ext,
    float* __restrict__ outp,
    float4* __restrict__ rec1,       // NVOX slots, g*256+i
    float4* __restrict__ rec2,       // 2*NVOX slots, g*512+2i+h
    int* __restrict__ cnt1g,         // [NGRP]
    int* __restrict__ cnt2g)         // [NGRP]
{
    __shared__ __align__(16) float s_buf[4290];      // 17160 B union
    __shared__ float s_ext[72];
    __shared__ float s_K[54];
    __shared__ int s_c1, s_c2;

    int tid = threadIdx.x;
    int lane = tid & 63;
    int wv = tid >> 6;
    int bid = blockIdx.x;

    if (bid < NTRB) {
        // ---- transpose tile ----
        int c = bid / 220;
        int p0 = (bid - c * 220) * 64;
        for (int r = wv; r < 64; r += 4)
            s_buf[r * 65 + lane] = feats[(c * 64 + r) * NPIX + p0 + lane];
        __syncthreads();
        for (int r = wv; r < 64; r += 4)
            featT[((c * NPIX) + p0 + r) * 64 + lane] = s_buf[lane * 65 + r];
    } else {
        // ---- geometry group (per-group slot output) ----
        int g = bid - NTRB;
        float4* s_r1 = (float4*)s_buf;               // 256 recs (4096 B)
        float4* s_r2 = ((float4*)s_buf) + 256;       // 512 recs (8192 B)
        if (tid == 0) { s_c1 = 0; s_c2 = 0; }
        if (tid >= 64 && tid < 136) {
            int i = tid - 64;
            s_ext[i] = ext[(i / 12) * 16 + (i % 12)];
        }
        if (tid >= 160 && tid < 214) {
            int i = tid - 160; int cam = i / 9; int e = i - cam * 9;
            s_K[i] = Kg[cam * 16 + (e / 3) * 4 + (e % 3)];
        }
        __syncthreads();
        int n = g * 256 + tid;
        if (n < NVOX) {
            #pragma clang fp contract(off)
            int xi = n % 100;
            int t = n / 100;
            int yi = t % 100;
            int zi = t / 100;
            float X = -50.0f + (float)xi;
            float Y = -50.0f + (float)yi;
            float Z = -15.0f + 1.5f * (float)zi;
            int cc = 0, cam0 = 0, cam1 = 0;
            float ax = 0.f, ay = 0.f, az = 0.f, bx = 0.f, by = 0.f, bz = 0.f;
            #pragma unroll
            for (int cam = 0; cam < NC; ++cam) {
                const float* E = s_ext + cam * 12;
                const float* Kk = s_K + cam * 9;
                float vl0 = E[0]*X + E[1]*Y + E[2]*Z + E[3];
                float vl1 = E[4]*X + E[5]*Y + E[6]*Z + E[7];
                float vl2 = E[8]*X + E[9]*Y + E[10]*Z + E[11];
                float c0 = Kk[0]*vl0 + Kk[1]*vl1 + Kk[2]*vl2;
                float c1 = Kk[3]*vl0 + Kk[4]*vl1 + Kk[5]*vl2;
                float c2 = Kk[6]*vl0 + Kk[7]*vl1 + Kk[8]*vl2;
                float pz = c2 + 1e-8f;
                float px = c0 / pz;
                float py = c1 / pz;
                float gx = (px / 159.0f - 0.5f) * 2.0f;
                float gy = (py / 87.0f - 0.5f) * 2.0f;
                float x = ((gx + 1.0f) * 0.5f) * 159.0f;
                float y = ((gy + 1.0f) * 0.5f) * 87.0f;
                float xr = rintf(x), yr = rintf(y);
                bool nv = (xr >= 0.0f) && (xr <= 159.0f) && (yr >= 0.0f) && (yr <= 87.0f);
                float mval = 0.0f;
                if (nv) mval = mask[(cam * HH + (int)yr) * WW + (int)xr];
                bool ok = (mval > 0.5f) && (vl2 > 0.0f) &&
                          !((gx > 1.0f) || (gx < -1.0f) || (gy > 1.0f) || (gy < -1.0f));
                if (ok) {
                    if (cc == 0) { ax = x; ay = y; az = vl2; cam0 = cam; }
                    else if (cc == 1) { bx = x; by = y; bz = vl2; cam1 = cam; }
                    ++cc;
                }
            }
            if (cc == 1) {
                int s = atomicAdd(&s_c1, 1);
                s_r1[s] = make_float4(ax, ay, az, __int_as_float((n << 3) | cam0));
            } else if (cc == 2) {
                int s = atomicAdd(&s_c2, 1);
                s_r2[2 * s + 0] = make_float4(ax, ay, az, __int_as_float((n << 3) | cam0));
                s_r2[2 * s + 1] = make_float4(bx, by, bz, __int_as_float((n << 3) | cam1));
            }
        }
        __syncthreads();
        int c1 = s_c1, c2 = s_c2;
        if (tid == 0) { cnt1g[g] = c1; cnt2g[g] = c2; }
        for (int i = tid; i < c1; i += 256) rec1[g * 256 + i] = s_r1[i];
        for (int i = tid; i < 2 * c2; i += 256) rec2[g * 512 + i] = s_r2[i];
    }

    // ---- grid-stride zero of the output window (independent of above) ----
    {
        float4* o4 = (float4*)outp;
        const int n4 = VPRE * NVOX / 4;
        const int stride = (NTRB + NGRP) * 256;
        for (int i = bid * 256 + tid; i < n4; i += stride)
            o4[i] = make_float4(0.f, 0.f, 0.f, 0.f);
    }
}

// single-wave inclusive prefix over NGRP counts: lane handles 13
// consecutive groups; cross-lane via shfl (no barriers inside).
__device__ __forceinline__ void scan_wave(const int* __restrict__ cg,
                                          int* __restrict__ s_P, int lane) {
    int base = lane * 13;
    int v[13];
    int sum = 0;
    #pragma unroll
    for (int i = 0; i < 13; ++i) {
        int idx = base + i;
        int x = (idx < NGRP) ? cg[idx] : 0;
        sum += x;
        v[i] = sum;                        // inclusive within lane
    }
    int s = sum;
    #pragma unroll
    for (int off = 1; off < 64; off <<= 1) {
        int y = __shfl_up(s, off, 64);
        if (lane >= off) s += y;
    }
    int excl = s - sum;                    // exclusive prefix of this lane
    #pragma unroll
    for (int i = 0; i < 13; ++i) {
        int idx = base + i;
        if (idx < NGRP) s_P[idx] = excl + v[i];
    }
}

__device__ __forceinline__ int bsearch_grp(const int* __restrict__ P, int k) {
    int lo = 0, hi = NGRP - 1;
    while (lo < hi) { int mid = (lo + hi) >> 1; if (P[mid] > k) hi = mid; else lo = mid + 1; }
    return lo;
}

// =====================================================================
// K2: comp over virtually-compacted 64-entry tiles. 256 threads = 4
// waves x 16 output rows. Changes vs r7: (a) wave-0 shuffle scan
// (no 16-barrier block scan), (b) 8-channel batched gather -> serial
// load chain 2 (was 4).
// =====================================================================
__global__ __launch_bounds__(256) void vox_comp2(
    const float* __restrict__ featT,
    const float* __restrict__ wno,   // [64][65]
    const float* __restrict__ bno,   // [64]
    const float* __restrict__ wo,    // [64][130]
    const float* __restrict__ bo,    // [64]
    float* __restrict__ outp,        // [64][200000]
    const float4* __restrict__ rec1,
    const float4* __restrict__ rec2,
    const int* __restrict__ cnt1g,
    const int* __restrict__ cnt2g)
{
    __shared__ __align__(16) float s_F[65 * 66];
    __shared__ float4 s_rec[128];
    __shared__ int s_vox[64];
    __shared__ int s_P1[NGRP];
    __shared__ int s_P2[NGRP];

    int tid = threadIdx.x;
    int lane = tid & 63;
    int wv = tid >> 6;                               // 0..3
    int wvu = __builtin_amdgcn_readfirstlane(wv);
    int obase = wvu * 16;
    int q8 = lane & 7;                               // channel octet
    int j8 = lane >> 3;                              // entry subgroup 0..7

    if (wv == 0) {
        scan_wave(cnt1g, s_P1, lane);
        scan_wave(cnt2g, s_P2, lane);
    }
    __syncthreads();
    int n1 = s_P1[NGRP - 1], n2 = s_P2[NGRP - 1];
    int T1 = (n1 + 63) >> 6;
    int T2 = (n2 + 63) >> 6;
    int TT = T1 + T2;

    for (int t = blockIdx.x; t < TT; t += gridDim.x) {
        if (t < T1) {
            // ---------------- count == 1 tile ----------------
            int e0 = t << 6;
            int tl = min(64, n1 - e0);
            if (tid < tl) {
                int k = e0 + tid;
                int g = bsearch_grp(s_P1, k);
                int l = k - ((g > 0) ? s_P1[g - 1] : 0);
                s_rec[tid] = rec1[g * 256 + l];
            }
            __syncthreads();
            #pragma unroll 1
            for (int u = 0; u < 2; ++u) {
                int e = wv + 4 * j8 + 32 * u;         // wave wv covers e ≡ wv (mod 4)
                if (e < tl) {
                    float4 r = s_rec[e];
                    int meta = __float_as_int(r.w);
                    int cam = meta & 7;
                    float4 fa, fb;
                    gather_bilin8(featT, q8, cam, r.x, r.y, fa, fb);
                    s_F[(8 * q8 + 0) * 66 + e] = fa.x;
                    s_F[(8 * q8 + 1) * 66 + e] = fa.y;
                    s_F[(8 * q8 + 2) * 66 + e] = fa.z;
                    s_F[(8 * q8 + 3) * 66 + e] = fa.w;
                    s_F[(8 * q8 + 4) * 66 + e] = fb.x;
                    s_F[(8 * q8 + 5) * 66 + e] = fb.y;
                    s_F[(8 * q8 + 6) * 66 + e] = fb.z;
                    s_F[(8 * q8 + 7) * 66 + e] = fb.w;
                    if (q8 == 0) { s_F[64 * 66 + e] = r.z / 100.0f; s_vox[e] = meta >> 3; }
                }
            }
            __syncthreads();
            float acc[16];
            #pragma unroll
            for (int o = 0; o < 16; ++o) acc[o] = bno[obase + o];
            for (int cg2 = 0; cg2 < 64; cg2 += 4) {
                float f0 = s_F[(cg2 + 0) * 66 + lane];
                float f1 = s_F[(cg2 + 1) * 66 + lane];
                float f2 = s_F[(cg2 + 2) * 66 + lane];
                float f3 = s_F[(cg2 + 3) * 66 + lane];
                #pragma unroll
                for (int o = 0; o < 16; ++o) {
                    const float* wr = wno + (obase + o) * 65 + cg2;
                    acc[o] += wr[0] * f0; acc[o] += wr[1] * f1;
                    acc[o] += wr[2] * f2; acc[o] += wr[3] * f3;
                }
            }
            {
                float fd = s_F[64 * 66 + lane];
                #pragma unroll
                for (int o = 0; o < 16; ++o) acc[o] += wno[(obase + o) * 65 + 64] * fd;
            }
            if (lane < tl) {
                size_t col = (size_t)s_vox[lane];
                #pragma unroll
                for (int o = 0; o < 16; ++o)
                    outp[(size_t)(obase + o) * NVOX + col] = elu1(acc[o]);
            }
            __syncthreads();
        } else {
            // ---------------- count == 2 tile: two passes ----------------
            int tt = t - T1;
            int e0 = tt << 6;
            int tl = min(64, n2 - e0);
            if (tid < 2 * tl) {
                int p = tid >> 1, h = tid & 1;
                int k = e0 + p;
                int g = bsearch_grp(s_P2, k);
                int l = k - ((g > 0) ? s_P2[g - 1] : 0);
                s_rec[tid] = rec2[g * 512 + 2 * l + h];
            }
            __syncthreads();
            // pass A gather: cams {0,3,4}
            #pragma unroll 1
            for (int u = 0; u < 2; ++u) {
                int e = wv + 4 * j8 + 32 * u;
                if (e < tl) {
                    float4 r0 = s_rec[2 * e + 0];
                    float4 r1 = s_rec[2 * e + 1];
                    int m0 = __float_as_int(r0.w), m1 = __float_as_int(r1.w);
                    int ca = m0 & 7, cb = m1 & 7;
                    float4 fga = make_float4(0.f, 0.f, 0.f, 0.f);
                    float4 fgb = make_float4(0.f, 0.f, 0.f, 0.f);
                    float dd = 0.0f;
                    if (!(ca == 1 || ca == 2 || ca == 5)) {
                        float4 ga, gb;
                        gather_bilin8(featT, q8, ca, r0.x, r0.y, ga, gb);
                        fga.x += ga.x; fga.y += ga.y; fga.z += ga.z; fga.w += ga.w;
                        fgb.x += gb.x; fgb.y += gb.y; fgb.z += gb.z; fgb.w += gb.w;
                        dd += r0.z / 100.0f;
                    }
                    if (!(cb == 1 || cb == 2 || cb == 5)) {
                        float4 ga, gb;
                        gather_bilin8(featT, q8, cb, r1.x, r1.y, ga, gb);
                        fga.x += ga.x; fga.y += ga.y; fga.z += ga.z; fga.w += ga.w;
                        fgb.x += gb.x; fgb.y += gb.y; fgb.z += gb.z; fgb.w += gb.w;
                        dd += r1.z / 100.0f;
                    }
                    s_F[(8 * q8 + 0) * 66 + e] = fga.x;
                    s_F[(8 * q8 + 1) * 66 + e] = fga.y;
                    s_F[(8 * q8 + 2) * 66 + e] = fga.z;
                    s_F[(8 * q8 + 3) * 66 + e] = fga.w;
                    s_F[(8 * q8 + 4) * 66 + e] = fgb.x;
                    s_F[(8 * q8 + 5) * 66 + e] = fgb.y;
                    s_F[(8 * q8 + 6) * 66 + e] = fgb.z;
                    s_F[(8 * q8 + 7) * 66 + e] = fgb.w;
                    if (q8 == 0) { s_F[64 * 66 + e] = dd; s_vox[e] = m0 >> 3; }
                }
            }
            __syncthreads();
            float acc[16];
            #pragma unroll
            for (int o = 0; o < 16; ++o) acc[o] = bo[obase + o];
            for (int cg2 = 0; cg2 < 64; cg2 += 4) {  // pass A compute: cols 0..64
                float f0 = s_F[(cg2 + 0) * 66 + lane];
                float f1 = s_F[(cg2 + 1) * 66 + lane];
                float f2 = s_F[(cg2 + 2) * 66 + lane];
                float f3 = s_F[(cg2 + 3) * 66 + lane];
                #pragma unroll
                for (int o = 0; o < 16; ++o) {
                    const float* wr = wo + (obase + o) * 130 + cg2;
                    acc[o] += wr[0] * f0; acc[o] += wr[1] * f1;
                    acc[o] += wr[2] * f2; acc[o] += wr[3] * f3;
                }
            }
            {
                float fd = s_F[64 * 66 + lane];
                #pragma unroll
                for (int o = 0; o < 16; ++o) acc[o] += wo[(obase + o) * 130 + 64] * fd;
            }
            __syncthreads();
            // pass B gather: cams {1,2,5}
            #pragma unroll 1
            for (int u = 0; u < 2; ++u) {
                int e = wv + 4 * j8 + 32 * u;
                if (e < tl) {
                    float4 r0 = s_rec[2 * e + 0];
                    float4 r1 = s_rec[2 * e + 1];
                    int m0 = __float_as_int(r0.w), m1 = __float_as_int(r1.w);
                    int ca = m0 & 7, cb = m1 & 7;
                    float4 fga = make_float4(0.f, 0.f, 0.f, 0.f);
                    float4 fgb = make_float4(0.f, 0.f, 0.f, 0.f);
                    float dd = 0.0f;
                    if (ca == 1 || ca == 2 || ca == 5) {
                        float4 ga, gb;
                        gather_bilin8(featT, q8, ca, r0.x, r0.y, ga, gb);
                        fga.x += ga.x; fga.y += ga.y; fga.z += ga.z; fga.w += ga.w;
                        fgb.x += gb.x; fgb.y += gb.y; fgb.z += gb.z; fgb.w += gb.w;
                        dd += r0.z / 100.0f;
                    }
                    if (cb == 1 || cb == 2 || cb == 5) {
                        float4 ga, gb;
                        gather_bilin8(featT, q8, cb, r1.x, r1.y, ga, gb);
                        fga.x += ga.x; fga.y += ga.y; fga.z += ga.z; fga.w += ga.w;
                        fgb.x += gb.x; fgb.y += gb.y; fgb.z += gb.z; fgb.w += gb.w;
                        dd += r1.z / 100.0f;
                    }
                    s_F[(8 * q8 + 0) * 66 + e] = fga.x;
                    s_F[(8 * q8 + 1) * 66 + e] = fga.y;
                    s_F[(8 * q8 + 2) * 66 + e] = fga.z;
                    s_F[(8 * q8 + 3) * 66 + e] = fga.w;
                    s_F[(8 * q8 + 4) * 66 + e] = fgb.x;
                    s_F[(8 * q8 + 5) * 66 + e] = fgb.y;
                    s_F[(8 * q8 + 6) * 66 + e] = fgb.z;
                    s_F[(8 * q8 + 7) * 66 + e] = fgb.w;
                    if (q8 == 0) s_F[64 * 66 + e] = dd;
                }
            }
            __syncthreads();
            for (int cg2 = 0; cg2 < 64; cg2 += 4) {  // pass B compute: cols 65..129
                float f0 = s_F[(cg2 + 0) * 66 + lane];
                float f1 = s_F[(cg2 + 1) * 66 + lane];
                float f2 = s_F[(cg2 + 2) * 66 + lane];
                float f3 = s_F[(cg2 + 3) * 66 + lane];
                #pragma unroll
                for (int o = 0; o < 16; ++o) {
                    const float* wr = wo + (obase + o) * 130 + 65 + cg2;
                    acc[o] += wr[0] * f0; acc[o] += wr[1] * f1;
                    acc[o] += wr[2] * f2; acc[o] += wr[3] * f3;
                }
            }
            {
                float fd = s_F[64 * 66 + lane];
                #pragma unroll
                for (int o = 0; o < 16; ++o) acc[o] += wo[(obase + o) * 130 + 129] * fd;
            }
            if (lane < tl) {
                size_t col = (size_t)s_vox[lane];
                #pragma unroll
                for (int o = 0; o < 16; ++o)
                    outp[(size_t)(obase + o) * NVOX + col] = elu1(acc[o]);
            }
            __syncthreads();
        }
    }
}

// =====================================================================
// FALLBACK PATH (round-3 proven 4-kernel chain, old workspace layout)
// =====================================================================
__global__ __launch_bounds__(256) void zero_out(float4* __restrict__ p, int n4) {
    int i = blockIdx.x * 256 + threadIdx.x;
    int stride = gridDim.x * 256;
    for (; i < n4; i += stride)
        p[i] = make_float4(0.f, 0.f, 0.f, 0.f);
}

__global__ __launch_bounds__(256) void transpose_feats(const float* __restrict__ in,
                                                       float* __restrict__ out,
                                                       int* __restrict__ cnt) {
    __shared__ float tile[64 * 65];
    if (cnt && blockIdx.x == 0 && threadIdx.x < 2) cnt[threadIdx.x] = 0;
    int blk = blockIdx.x;            // 6 * 220
    int c = blk / 220;
    int p0 = (blk - c * 220) * 64;
    int tid = threadIdx.x;
    int lane = tid & 63;
    int quad = tid >> 6;
    for (int r = quad; r < 64; r += 4)
        tile[r * 65 + lane] = in[(c * 64 + r) * NPIX + p0 + lane];
    __syncthreads();
    for (int r = quad; r < 64; r += 4)
        out[((c * NPIX) + p0 + r) * 64 + lane] = tile[lane * 65 + r];
}

__global__ __launch_bounds__(256) void vox_geom(
    const float* __restrict__ mask,
    const float* __restrict__ Kg,
    const float* __restrict__ ext,
    float4* __restrict__ rec1,
    float4* __restrict__ rec2,
    int* __restrict__ cnt)
{
    __shared__ float s_ext[72];
    __shared__ float s_K[54];
    __shared__ float4 s_r1[256];
    __shared__ float4 s_r2[512];
    __shared__ int s_c1, s_c2, s_b1, s_b2;

    int tid = threadIdx.x;
    if (tid == 0) { s_c1 = 0; s_c2 = 0; }
    if (tid >= 64 && tid < 136) {
        int i = tid - 64;
        s_ext[i] = ext[(i / 12) * 16 + (i % 12)];
    }
    if (tid >= 160 && tid < 214) {
        int i = tid - 160; int cam = i / 9; int e = i - cam * 9;
        s_K[i] = Kg[cam * 16 + (e / 3) * 4 + (e % 3)];
    }
    __syncthreads();

    int n = blockIdx.x * 256 + tid;
    if (n < NVOX) {
        #pragma clang fp contract(off)
        int xi = n % 100;
        int t = n / 100;
        int yi = t % 100;
        int zi = t / 100;
        float X = -50.0f + (float)xi;
        float Y = -50.0f + (float)yi;
        float Z = -15.0f + 1.5f * (float)zi;
        int cc = 0, cam0 = 0, cam1 = 0;
        float ax = 0.f, ay = 0.f, az = 0.f, bx = 0.f, by = 0.f, bz = 0.f;
        #pragma unroll
        for (int cam = 0; cam < NC; ++cam) {
            const float* E = s_ext + cam * 12;
            const float* Kk = s_K + cam * 9;
            float vl0 = E[0]*X + E[1]*Y + E[2]*Z + E[3];
            float vl1 = E[4]*X + E[5]*Y + E[6]*Z + E[7];
            float vl2 = E[8]*X + E[9]*Y + E[10]*Z + E[11];
            float c0 = Kk[0]*vl0 + Kk[1]*vl1 + Kk[2]*vl2;
            float c1 = Kk[3]*vl0 + Kk[4]*vl1 + Kk[5]*vl2;
            float c2 = Kk[6]*vl0 + Kk[7]*vl1 + Kk[8]*vl2;
            float pz = c2 + 1e-8f;
            float px = c0 / pz;
            float py = c1 / pz;
            float gx = (px / 159.0f - 0.5f) * 2.0f;
            float gy = (py / 87.0f - 0.5f) * 2.0f;
            float x = ((gx + 1.0f) * 0.5f) * 159.0f;
            float y = ((gy + 1.0f) * 0.5f) * 87.0f;
            float xr = rintf(x), yr = rintf(y);
            bool nv = (xr >= 0.0f) && (xr <= 159.0f) && (yr >= 0.0f) && (yr <= 87.0f);
            float mval = 0.0f;
            if (nv) mval = mask[(cam * HH + (int)yr) * WW + (int)xr];
            bool ok = (mval > 0.5f) && (vl2 > 0.0f) &&
                      !((gx > 1.0f) || (gx < -1.0f) || (gy > 1.0f) || (gy < -1.0f));
            if (ok) {
                if (cc == 0) { ax = x; ay = y; az = vl2; cam0 = cam; }
                else if (cc == 1) { bx = x; by = y; bz = vl2; cam1 = cam; }
                ++cc;
            }
        }
        if (cc == 1) {
            int s = atomicAdd(&s_c1, 1);
            s_r1[s] = make_float4(ax, ay, az, __int_as_float((n << 3) | cam0));
        } else if (cc == 2) {
            int s = atomicAdd(&s_c2, 1);
            s_r2[2 * s + 0] = make_float4(ax, ay, az, __int_as_float((n << 3) | cam0));
            s_r2[2 * s + 1] = make_float4(bx, by, bz, __int_as_float((n << 3) | cam1));
        }
    }
    __syncthreads();
    if (tid == 0) {
        s_b1 = atomicAdd(cnt + 0, s_c1);
        s_b2 = atomicAdd(cnt + 1, s_c2);
    }
    __syncthreads();
    int c1 = s_c1, c2 = s_c2, b1 = s_b1, b2 = s_b2;
    for (int i = tid; i < c1; i += 256) rec1[b1 + i] = s_r1[i];
    for (int i = tid; i < 2 * c2; i += 256) rec2[2 * b2 + i] = s_r2[i];
}

__global__ __launch_bounds__(256) void vox_comp(
    const float* __restrict__ featT,
    const float* __restrict__ wno,
    const float* __restrict__ bno,
    const float* __restrict__ wo,
    const float* __restrict__ bo,
    float* __restrict__ outp,
    const float4* __restrict__ rec1,
    const float4* __restrict__ rec2,
    const int* __restrict__ cnt)
{
    __shared__ float s_F[65 * 66];
    __shared__ float4 s_rec[128];
    __shared__ int s_vox[64];

    int tid = threadIdx.x;
    int lane = tid & 63;
    int wv = tid >> 6;
    int wvu = __builtin_amdgcn_readfirstlane(wv);
    int obase = wvu * 16;

    int n1 = cnt[0], n2 = cnt[1];
    int T1 = (n1 + 63) >> 6;
    int T2 = (n2 + 63) >> 6;
    int TT = T1 + T2;

    for (int t = blockIdx.x; t < TT; t += gridDim.x) {
        if (t < T1) {
            int e0 = t << 6;
            int tl = min(64, n1 - e0);
            if (tid < tl) s_rec[tid] = rec1[e0 + tid];
            __syncthreads();
            for (int e = wv; e < tl; e += 4) {
                float4 r = s_rec[e];
                int meta = __float_as_int(r.w);
                int cam = meta & 7;
                float fv = gather_bilin(featT, 1, lane, cam, r.x, r.y);
                s_F[lane * 66 + e] = fv;
                if (lane == 0) { s_F[64 * 66 + e] = r.z / 100.0f; s_vox[e] = meta >> 3; }
            }
            __syncthreads();
            float acc[16];
            #pragma unroll
            for (int o = 0; o < 16; ++o) acc[o] = bno[obase + o];
            for (int cg2 = 0; cg2 < 64; cg2 += 4) {
                float f0 = s_F[(cg2 + 0) * 66 + lane];
                float f1 = s_F[(cg2 + 1) * 66 + lane];
                float f2 = s_F[(cg2 + 2) * 66 + lane];
                float f3 = s_F[(cg2 + 3) * 66 + lane];
                #pragma unroll
                for (int o = 0; o < 16; ++o) {
                    const float* wr = wno + (obase + o) * 65 + cg2;
                    acc[o] += wr[0] * f0; acc[o] += wr[1] * f1;
                    acc[o] += wr[2] * f2; acc[o] += wr[3] * f3;
                }
            }
            {
                float fd = s_F[64 * 66 + lane];
                #pragma unroll
                for (int o = 0; o < 16; ++o) acc[o] += wno[(obase + o) * 65 + 64] * fd;
            }
            if (lane < tl) {
                size_t col = (size_t)s_vox[lane];
                #pragma unroll
                for (int o = 0; o < 16; ++o)
                    outp[(size_t)(obase + o) * NVOX + col] = elu1(acc[o]);
            }
            __syncthreads();
        } else {
            int tt = t - T1;
            int e0 = tt << 6;
            int tl = min(64, n2 - e0);
            if (tid < 2 * tl) s_rec[tid] = rec2[2 * e0 + tid];
            __syncthreads();
            for (int e = wv; e < tl; e += 4) {
                float4 r0 = s_rec[2 * e + 0];
                float4 r1 = s_rec[2 * e + 1];
                int m0 = __float_as_int(r0.w), m1 = __float_as_int(r1.w);
                int ca = m0 & 7, cb = m1 & 7;
                float fg = 0.0f, dd = 0.0f;
                if (!(ca == 1 || ca == 2 || ca == 5)) {
                    fg += gather_bilin(featT, 1, lane, ca, r0.x, r0.y);
                    dd += r0.z / 100.0f;
                }
                if (!(cb == 1 || cb == 2 || cb == 5)) {
                    fg += gather_bilin(featT, 1, lane, cb, r1.x, r1.y);
                    dd += r1.z / 100.0f;
                }
                s_F[lane * 66 + e] = fg;
                if (lane == 0) { s_F[64 * 66 + e] = dd; s_vox[e] = m0 >> 3; }
            }
            __syncthreads();
            float acc[16];
            #pragma unroll
            for (int o = 0; o < 16; ++o) acc[o] = bo[obase + o];
            for (int cg2 = 0; cg2 < 64; cg2 += 4) {
                float f0 = s_F[(cg2 + 0) * 66 + lane];
                float f1 = s_F[(cg2 + 1) * 66 + lane];
                float f2 = s_F[(cg2 + 2) * 66 + lane];
                float f3 = s_F[(cg2 + 3) * 66 + lane];
                #pragma unroll
                for (int o = 0; o < 16; ++o) {
                    const float* wr = wo + (obase + o) * 130 + cg2;
                    acc[o] += wr[0] * f0; acc[o] += wr[1] * f1;
                    acc[o] += wr[2] * f2; acc[o] += wr[3] * f3;
                }
            }
            {
                float fd = s_F[64 * 66 + lane];
                #pragma unroll
                for (int o = 0; o < 16; ++o) acc[o] += wo[(obase + o) * 130 + 64] * fd;
            }
            __syncthreads();
            for (int e = wv; e < tl; e += 4) {
                float4 r0 = s_rec[2 * e + 0];
                float4 r1 = s_rec[2 * e + 1];
                int m0 = __float_as_int(r0.w), m1 = __float_as_int(r1.w);
                int ca = m0 & 7, cb = m1 & 7;
                float fg = 0.0f, dd = 0.0f;
                if (ca == 1 || ca == 2 || ca == 5) {
                    fg += gather_bilin(featT, 1, lane, ca, r0.x, r0.y);
                    dd += r0.z / 100.0f;
                }
                if (cb == 1 || cb == 2 || cb == 5) {
                    fg += gather_bilin(featT, 1, lane, cb, r1.x, r1.y);
                    dd += r1.z / 100.0f;
                }
                s_F[lane * 66 + e] = fg;
                if (lane == 0) s_F[64 * 66 + e] = dd;
            }
            __syncthreads();
            for (int cg2 = 0; cg2 < 64; cg2 += 4) {
                float f0 = s_F[(cg2 + 0) * 66 + lane];
                float f1 = s_F[(cg2 + 1) * 66 + lane];
                float f2 = s_F[(cg2 + 2) * 66 + lane];
                float f3 = s_F[(cg2 + 3) * 66 + lane];
                #pragma unroll
                for (int o = 0; o < 16; ++o) {
                    const float* wr = wo + (obase + o) * 130 + 65 + cg2;
                    acc[o] += wr[0] * f0; acc[o] += wr[1] * f1;
                    acc[o] += wr[2] * f2; acc[o] += wr[3] * f3;
                }
            }
            {
                float fd = s_F[64 * 66 + lane];
                #pragma unroll
                for (int o = 0; o < 16; ++o) acc[o] += wo[(obase + o) * 130 + 129] * fd;
            }
            if (lane < tl) {
                size_t col = (size_t)s_vox[lane];
                #pragma unroll
                for (int o = 0; o < 16; ++o)
                    outp[(size_t)(obase + o) * NVOX + col] = elu1(acc[o]);
            }
            __syncthreads();
        }
    }
}

extern "C" void kernel_launch(void* const* d_in, const int* in_sizes, int n_in,
                              void* d_out, int out_size, void* d_ws, size_t ws_size,
                              hipStream_t stream) {
    const float* feats = (const float*)d_in[0];
    const float* mask  = (const float*)d_in[1];
    const float* Kg    = (const float*)d_in[2];
    const float* ext   = (const float*)d_in[3];
    const float* wno   = (const float*)d_in[4];
    const float* bno   = (const float*)d_in[5];
    const float* wo    = (const float*)d_in[6];
    const float* bo    = (const float*)d_in[7];
    float* outp = (float*)d_out;
    float* featT = (float*)d_ws;

    if (ws_size >= WS_NEED) {
        // ---- preferred: 2-dispatch atomic-free compaction path ----
        int* cnt1g = (int*)((char*)d_ws + CNT1_OFF);
        int* cnt2g = (int*)((char*)d_ws + CNT2_OFF);
        float4* rec1 = (float4*)((char*)d_ws + REC1_OFF);
        float4* rec2 = (float4*)((char*)d_ws + REC2_OFF);
        vox_prep<<<NTRB + NGRP, 256, 0, stream>>>(feats, featT, mask, Kg, ext,
                                                  outp, rec1, rec2, cnt1g, cnt2g);
        vox_comp2<<<2048, 256, 0, stream>>>(featT, wno, bno, wo, bo, outp,
                                            rec1, rec2, cnt1g, cnt2g);
    } else if (ws_size >= WS_NEED_OLD) {
        // ---- fallback: round-3 proven 4-kernel chain ----
        int* cnt = (int*)((char*)d_ws + OCNT_OFF);
        float4* rec1 = (float4*)((char*)d_ws + OREC1_OFF);
        float4* rec2 = (float4*)((char*)d_ws + OREC2_OFF);
        zero_out<<<2048, 256, 0, stream>>>((float4*)d_out,
                                           (int)((size_t)VPRE * NVOX / 4));
        transpose_feats<<<NC * 220, 256, 0, stream>>>(feats, featT, cnt);
        vox_geom<<<(NVOX + 255) / 256, 256, 0, stream>>>(mask, Kg, ext,
                                                         rec1, rec2, cnt);
        vox_comp<<<2048, 256, 0, stream>>>(featT, wno, bno, wo, bo, outp,
                                           rec1, rec2, cnt);
    } else {
        zero_out<<<2048, 256, 0, stream>>>((float4*)d_out,
                                           (int)((size_t)VPRE * NVOX / 4));
    }
}